// Round 8
// baseline (335.276 us; speedup 1.0000x reference)
//
#include <hip/hip_runtime.h>

#define N_NODES 50000
#define N_EDGES 10000
#define NNZ     800000
#define C       256
#define SLOPE   0.01f
#define KTOT    50048   // node count padded to multiple of 64
#define KCHUNK  1088    // 17 * 64
#define NZB     46      // KTOT / KCHUNK
#define MPAD    10048   // edge count padded to multiple of 64

#define NB      250     // coarse buckets per side
#define EB_E    40      // edges per bucket   (250*40  = 10000)
#define EB_N    200     // nodes per bucket   (250*200 = 50000)
#define CHUNK   3125    // NNZ / 256 blocks
#define CAP     6000    // LDS item capacity in bucket_sort (mean 3200, sd ~57)

// ---- workspace layout (bytes) ----
#define OFF_CC_E    0          // 250*4 coarse counts (edge)
#define OFF_CC_N    1024       // 250*4 coarse counts (node)
#define OFF_CUR_E   2048       // 250*4 scatter cursors
#define OFF_CUR_N   3072       // 250*4
#define OFF_G       4096       // 256*256*4
#define ZERO_BYTES  266240     // zero region [0, ZERO_BYTES), /16 ok
#define OFF_CB_E    266240     // 251*4 coarse bases (edge)
#define OFF_CB_N    267264     // 251*4 coarse bases (node)
#define OFF_RS_N    268288     // 50001*4 (written by bucket_sort)
#define OFF_RS_E    468480     // 10001*4 (written by bucket_sort)
#define OFF_BUF_E   508672     // 800000*4 bucketed items (edge side)
#define OFF_BUF_N   3708672    // 800000*4 bucketed items (node side)
#define OFF_CSR_E   6908672    // 800000*4 node ids grouped by edge
#define OFF_CSR_N   10108672   // 800000*4 edge ids grouped by node
#define OFF_EMBH    13308672   // 50000*256*2 bf16 (dead after edge_aggregate)
#define OFF_YT      13308672   // 256*50048*2 bf16 — ALIASES embh (embh dead first);
                               // ends at 38,933,248 (== OFF_EACC, no overlap)
#define OFF_EACC    38933248   // 10048*256*2 bf16 (dead after edge_gemm)
#define OFF_E2      44077824   // 10048*256*2 bf16
#define OFF_CWH     49222400   // 256*256*2 bf16 conv_w  -> end 49,353,472

typedef __attribute__((ext_vector_type(8))) short short8;
typedef __attribute__((ext_vector_type(4))) float floatx4;

static __device__ __forceinline__ unsigned short f2bf(float f) {
    unsigned int u = __float_as_uint(f);
    u = (u + 0x7fffu + ((u >> 16) & 1u)) >> 16;   // RNE
    return (unsigned short)u;
}

// unpack uint4 (8 bf16) and accumulate into a[0..7]
static __device__ __forceinline__ void acc_bf8(const uint4 d, float* a) {
    a[0] += __uint_as_float(d.x << 16);
    a[1] += __uint_as_float(d.x & 0xffff0000u);
    a[2] += __uint_as_float(d.y << 16);
    a[3] += __uint_as_float(d.y & 0xffff0000u);
    a[4] += __uint_as_float(d.z << 16);
    a[5] += __uint_as_float(d.z & 0xffff0000u);
    a[6] += __uint_as_float(d.w << 16);
    a[7] += __uint_as_float(d.w & 0xffff0000u);
}

// this half-wave accumulates rows csr[s+half], csr[s+half+2], ... < t.
// Index loads are same-address broadcast loads (safe under divergence).
// 8 independent index->row chains in flight.
static __device__ __forceinline__ void gather_rows(const uint4* __restrict__ tbl4,
                                                   const int* __restrict__ csr,
                                                   int s, int t, int half, int l32,
                                                   float* a) {
    int i = s + half;
    for (; i + 14 < t; i += 16) {
        int e0 = csr[i],      e1 = csr[i + 2],  e2 = csr[i + 4],  e3 = csr[i + 6];
        int e4 = csr[i + 8],  e5 = csr[i + 10], e6 = csr[i + 12], e7 = csr[i + 14];
        uint4 d0 = tbl4[(size_t)e0 * 32 + l32];
        uint4 d1 = tbl4[(size_t)e1 * 32 + l32];
        uint4 d2 = tbl4[(size_t)e2 * 32 + l32];
        uint4 d3 = tbl4[(size_t)e3 * 32 + l32];
        uint4 d4 = tbl4[(size_t)e4 * 32 + l32];
        uint4 d5 = tbl4[(size_t)e5 * 32 + l32];
        uint4 d6 = tbl4[(size_t)e6 * 32 + l32];
        uint4 d7 = tbl4[(size_t)e7 * 32 + l32];
        acc_bf8(d0, a); acc_bf8(d1, a); acc_bf8(d2, a); acc_bf8(d3, a);
        acc_bf8(d4, a); acc_bf8(d5, a); acc_bf8(d6, a); acc_bf8(d7, a);
    }
    for (; i < t; i += 2) {
        uint4 d = tbl4[(size_t)csr[i] * 32 + l32];
        acc_bf8(d, a);
    }
}

__global__ __launch_bounds__(256) void zero_kernel(float4* __restrict__ p, int n4) {
    int i = blockIdx.x * 256 + threadIdx.x;
    if (i < n4) p[i] = make_float4(0.f, 0.f, 0.f, 0.f);
}

// generic f32 -> bf16 cast (8 elems/thread)
__global__ __launch_bounds__(256) void cast_bf16_kernel(const float4* __restrict__ src4,
                                                        uint4* __restrict__ dst4, int n8) {
    int i = blockIdx.x * 256 + threadIdx.x;
    if (i >= n8) return;
    float4 f0 = src4[2 * i], f1 = src4[2 * i + 1];
    uint4 o;
    o.x = f2bf(f0.x) | ((unsigned)f2bf(f0.y) << 16);
    o.y = f2bf(f0.z) | ((unsigned)f2bf(f0.w) << 16);
    o.z = f2bf(f1.x) | ((unsigned)f2bf(f1.y) << 16);
    o.w = f2bf(f1.z) | ((unsigned)f2bf(f1.w) << 16);
    dst4[i] = o;
}

// coarse histogram: per-block LDS hist over 250 buckets/side, then one global
// atomic per (block,bucket)
__global__ __launch_bounds__(256) void coarse_count_kernel(const int* __restrict__ node_idx,
                                                           const int* __restrict__ edge_idx,
                                                           int* __restrict__ cc_e,
                                                           int* __restrict__ cc_n) {
    __shared__ int he[NB], hn[NB];
    int tid = threadIdx.x;
    int base = blockIdx.x * CHUNK;
    for (int i = tid; i < NB; i += 256) { he[i] = 0; hn[i] = 0; }
    __syncthreads();
    for (int i = tid; i < CHUNK; i += 256) {
        atomicAdd(&he[edge_idx[base + i] / EB_E], 1);
        atomicAdd(&hn[node_idx[base + i] / EB_N], 1);
    }
    __syncthreads();
    for (int k = tid; k < NB; k += 256) {
        if (he[k]) atomicAdd(&cc_e[k], he[k]);
        if (hn[k]) atomicAdd(&cc_n[k], hn[k]);
    }
}

// single-block exclusive scan of both coarse-count arrays -> coarse bases
__global__ __launch_bounds__(256) void coarse_scan_kernel(const int* __restrict__ cc_e,
                                                          const int* __restrict__ cc_n,
                                                          int* __restrict__ cb_e,
                                                          int* __restrict__ cb_n) {
    __shared__ int tmp[256];
    int tid = threadIdx.x;
    int v = (tid < NB) ? cc_e[tid] : 0;
    tmp[tid] = v;
    __syncthreads();
    for (int off = 1; off < 256; off <<= 1) {
        int t = (tid >= off) ? tmp[tid - off] : 0;
        __syncthreads();
        tmp[tid] += t;
        __syncthreads();
    }
    if (tid < NB) cb_e[tid + 1] = tmp[tid];
    if (tid == 0) cb_e[0] = 0;
    __syncthreads();
    v = (tid < NB) ? cc_n[tid] : 0;
    tmp[tid] = v;
    __syncthreads();
    for (int off = 1; off < 256; off <<= 1) {
        int t = (tid >= off) ? tmp[tid - off] : 0;
        __syncthreads();
        tmp[tid] += t;
        __syncthreads();
    }
    if (tid < NB) cb_n[tid + 1] = tmp[tid];
    if (tid == 0) cb_n[0] = 0;
}

// pass 1: scatter incidences into coarse buckets (both sides), line-dense writes
__global__ __launch_bounds__(256) void bucket_scatter_kernel(const int* __restrict__ node_idx,
                                                             const int* __restrict__ edge_idx,
                                                             const int* __restrict__ cb_e,
                                                             const int* __restrict__ cb_n,
                                                             int* __restrict__ cur_e,
                                                             int* __restrict__ cur_n,
                                                             int* __restrict__ buf_e,
                                                             int* __restrict__ buf_n) {
    __shared__ int he[NB], hn[NB], be[NB], bn[NB];
    int tid = threadIdx.x;
    int base = blockIdx.x * CHUNK;
    for (int i = tid; i < NB; i += 256) { he[i] = 0; hn[i] = 0; }
    __syncthreads();
    for (int i = tid; i < CHUNK; i += 256) {
        int e = edge_idx[base + i], v = node_idx[base + i];
        atomicAdd(&he[e / EB_E], 1);
        atomicAdd(&hn[v / EB_N], 1);
    }
    __syncthreads();
    for (int k = tid; k < NB; k += 256) {
        int c = he[k];
        be[k] = cb_e[k] + (c ? atomicAdd(&cur_e[k], c) : 0);
        int cn = hn[k];
        bn[k] = cb_n[k] + (cn ? atomicAdd(&cur_n[k], cn) : 0);
    }
    __syncthreads();
    for (int i = tid; i < NB; i += 256) { he[i] = 0; hn[i] = 0; }
    __syncthreads();
    for (int i = tid; i < CHUNK; i += 256) {
        int e = edge_idx[base + i], v = node_idx[base + i];
        int ke = e / EB_E, kn = v / EB_N;
        int oe = atomicAdd(&he[ke], 1);
        buf_e[be[ke] + oe] = (v << 6) | (e - ke * EB_E);
        int on = atomicAdd(&hn[kn], 1);
        buf_n[bn[kn] + on] = (e << 8) | (v - kn * EB_N);
    }
}

// pass 2: per-bucket LDS counting sort -> final CSR + emit fine rs
__global__ __launch_bounds__(256) void bucket_sort_kernel(const int* __restrict__ buf_e,
                                                          const int* __restrict__ buf_n,
                                                          const int* __restrict__ cb_e,
                                                          const int* __restrict__ cb_n,
                                                          int* __restrict__ csr_e,
                                                          int* __restrict__ csr_n,
                                                          int* __restrict__ rs_e,
                                                          int* __restrict__ rs_n) {
    __shared__ int A[CAP];
    __shared__ int h[EB_N], bs[EB_N];
    int tid = threadIdx.x;
    bool edgeSide = blockIdx.x < NB;
    int k = edgeSide ? blockIdx.x : blockIdx.x - NB;
    int eb = edgeSide ? EB_E : EB_N;
    int shift = edgeSide ? 6 : 8;
    int mask = (1 << shift) - 1;
    const int* cb  = edgeSide ? cb_e : cb_n;
    const int* buf = edgeSide ? buf_e : buf_n;
    int* csr       = edgeSide ? csr_e : csr_n;
    int* rs        = edgeSide ? rs_e : rs_n;
    int base = cb[k];
    int cnt = cb[k + 1] - base;
    for (int i = tid; i < eb; i += 256) h[i] = 0;
    __syncthreads();
    for (int i = tid; i < cnt; i += 256) {
        int it = buf[base + i];
        if (i < CAP) A[i] = it;
        atomicAdd(&h[it & mask], 1);
    }
    __syncthreads();
    if (tid == 0) {
        int s = 0;
        for (int j = 0; j < eb; j++) { bs[j] = s; s += h[j]; }
    }
    __syncthreads();
    for (int j = tid; j < eb; j += 256) {
        rs[k * eb + j] = base + bs[j];
        h[j] = 0;
    }
    if (tid == 0 && k == NB - 1) rs[edgeSide ? N_EDGES : N_NODES] = NNZ;
    __syncthreads();
    for (int i = tid; i < cnt; i += 256) {
        int it = (i < CAP) ? A[i] : buf[base + i];
        int loc = it & mask;
        int off = bs[loc] + atomicAdd(&h[loc], 1);
        csr[base + off] = it >> shift;
    }
}

// one wave per hyperedge; 8-deep pipelined gathers; bf16 output (padded rows zeroed)
__global__ __launch_bounds__(256) void edge_aggregate_kernel(const uint4* __restrict__ embh4,
                                                             const int* __restrict__ csr_e,
                                                             const int* __restrict__ rs_e,
                                                             unsigned short* __restrict__ e_acc_h) {
    int e = blockIdx.x * 4 + (threadIdx.x >> 6);
    int lane = threadIdx.x & 63;
    int half = lane >> 5, l32 = lane & 31;
    int s = 0, t = 0;
    if (e < N_EDGES) { s = rs_e[e]; t = rs_e[e + 1]; }
    float a[8] = {0.f, 0.f, 0.f, 0.f, 0.f, 0.f, 0.f, 0.f};
    gather_rows(embh4, csr_e, s, t, half, l32, a);
    #pragma unroll
    for (int j = 0; j < 8; j++) a[j] += __shfl_xor(a[j], 32);
    if (half == 0) {
        uint4 o;
        o.x = f2bf(a[0]) | ((unsigned)f2bf(a[1]) << 16);
        o.y = f2bf(a[2]) | ((unsigned)f2bf(a[3]) << 16);
        o.z = f2bf(a[4]) | ((unsigned)f2bf(a[5]) << 16);
        o.w = f2bf(a[6]) | ((unsigned)f2bf(a[7]) << 16);
        ((uint4*)(e_acc_h + (size_t)e * C))[l32] = o;
    }
}

// e2[m][n] = Binv[m] * sum_k e_acc[m][k] * conv_w[n][k] via MFMA; grid (157,4)
__global__ __launch_bounds__(256) void edge_gemm_mfma_kernel(const unsigned short* __restrict__ e_acc_h,
                                                             const unsigned short* __restrict__ cwh,
                                                             const int* __restrict__ rs_e,
                                                             unsigned short* __restrict__ e2h) {
    __shared__ __align__(16) unsigned short As[64 * 72];
    __shared__ __align__(16) unsigned short Bs[64 * 72];
    int i0 = blockIdx.x * 64, j0 = blockIdx.y * 64;
    int tid = threadIdx.x;
    int w = tid >> 6, lane = tid & 63;
    int col = lane & 15, quad = lane >> 4;
    floatx4 acc[4] = {};
    for (int step = 0; step < 4; step++) {
        int kb = step * 64;
        __syncthreads();
        #pragma unroll
        for (int l = 0; l < 2; l++) {
            int slot = tid + l * 256;
            int row = slot >> 3, grp = slot & 7;
            uint4 da = *(const uint4*)(e_acc_h + (size_t)(i0 + row) * C + kb + grp * 8);
            *(uint4*)(&As[row * 72 + grp * 8]) = da;
            uint4 db = *(const uint4*)(cwh + (size_t)(j0 + row) * C + kb + grp * 8);
            *(uint4*)(&Bs[row * 72 + grp * 8]) = db;
        }
        __syncthreads();
        #pragma unroll
        for (int sub = 0; sub < 2; sub++) {
            short8 a = *(const short8*)(&As[(w * 16 + col) * 72 + sub * 32 + quad * 8]);
            #pragma unroll
            for (int jt = 0; jt < 4; jt++) {
                short8 b = *(const short8*)(&Bs[(jt * 16 + col) * 72 + sub * 32 + quad * 8]);
                acc[jt] = __builtin_amdgcn_mfma_f32_16x16x32_bf16(a, b, acc[jt], 0, 0, 0);
            }
        }
    }
    // epilogue: binv scale + bf16 store
    #pragma unroll
    for (int r = 0; r < 4; r++) {
        int m = i0 + w * 16 + quad * 4 + r;
        if (m < N_EDGES) {
            int deg = rs_e[m + 1] - rs_e[m];
            float binv = (deg > 0) ? 1.0f / (float)deg : 0.0f;
            #pragma unroll
            for (int jt = 0; jt < 4; jt++)
                e2h[(size_t)m * C + j0 + jt * 16 + col] = f2bf(acc[jt][r] * binv);
        }
    }
}

// 32 nodes per block (4 waves x 8 nodes); 8-deep pipelined gathers; fused
// Dinv/bias/lrelu; write yT (transposed via LDS)
__global__ __launch_bounds__(256) void node_aggregate_t_kernel(const uint4* __restrict__ e2h4,
                                                               const int* __restrict__ csr_n,
                                                               const int* __restrict__ rs_n,
                                                               const float* __restrict__ conv_b,
                                                               unsigned short* __restrict__ yT) {
    __shared__ __align__(16) unsigned short T[32][256];  // [node][ch]
    int n0 = blockIdx.x * 32;
    int tid = threadIdx.x;
    int w = tid >> 6, lane = tid & 63;
    int half = lane >> 5, l32 = lane & 31;
    int base = n0 + w * 8;
    // __shfl below runs with ALL 64 lanes active (uniform q loop) — safe
    int rsv = rs_n[min(base + lane, N_NODES)];
    float4 b0 = ((const float4*)conv_b)[l32 * 2];
    float4 b1 = ((const float4*)conv_b)[l32 * 2 + 1];
    float bb[8] = {b0.x, b0.y, b0.z, b0.w, b1.x, b1.y, b1.z, b1.w};
    for (int q = 0; q < 8; q++) {
        int v = base + q;
        int s = __shfl(rsv, q), t = __shfl(rsv, q + 1);
        float a[8] = {0.f, 0.f, 0.f, 0.f, 0.f, 0.f, 0.f, 0.f};
        gather_rows(e2h4, csr_n, s, t, half, l32, a);
        #pragma unroll
        for (int j = 0; j < 8; j++) a[j] += __shfl_xor(a[j], 32);
        float dinv = (t > s) ? 1.0f / (float)(t - s) : 0.0f;
        unsigned int pk[4];
        #pragma unroll
        for (int j = 0; j < 4; j++) {
            float r0 = a[2 * j] * dinv + bb[2 * j];
            float r1 = a[2 * j + 1] * dinv + bb[2 * j + 1];
            r0 = (r0 > 0.f) ? r0 : SLOPE * r0;
            r1 = (r1 > 0.f) ? r1 : SLOPE * r1;
            if (v >= N_NODES) { r0 = 0.f; r1 = 0.f; }   // zero-pad rows
            pk[j] = f2bf(r0) | ((unsigned)f2bf(r1) << 16);
        }
        if (half == 0) {
            uint4 o; o.x = pk[0]; o.y = pk[1]; o.z = pk[2]; o.w = pk[3];
            *(uint4*)(&T[w * 8 + q][l32 * 8]) = o;
        }
    }
    __syncthreads();
    int ch = tid;
    #pragma unroll
    for (int jj = 0; jj < 4; jj++) {
        uint4 o;
        o.x = T[jj * 8 + 0][ch] | ((unsigned)T[jj * 8 + 1][ch] << 16);
        o.y = T[jj * 8 + 2][ch] | ((unsigned)T[jj * 8 + 3][ch] << 16);
        o.z = T[jj * 8 + 4][ch] | ((unsigned)T[jj * 8 + 5][ch] << 16);
        o.w = T[jj * 8 + 6][ch] | ((unsigned)T[jj * 8 + 7][ch] << 16);
        *(uint4*)(yT + (size_t)ch * KTOT + n0 + jj * 8) = o;
    }
}

// g += yT-tile^T yT-tile via MFMA, SYMMETRY-aware: only 10 upper-tri tile
// pairs computed; off-diagonal results mirrored. grid (10, NZB)
__global__ __launch_bounds__(256) void gram_mfma_kernel(const unsigned short* __restrict__ yT,
                                                        float* __restrict__ g) {
    static const int PI[10] = {0, 0, 0, 0, 1, 1, 1, 2, 2, 3};
    static const int PJ[10] = {0, 1, 2, 3, 1, 2, 3, 2, 3, 3};
    __shared__ __align__(16) unsigned short As[64 * 72];  // [col][k], stride 72
    __shared__ __align__(16) unsigned short Bs[64 * 72];
    int i0 = PI[blockIdx.x] * 64, j0 = PJ[blockIdx.x] * 64;
    int kb0 = blockIdx.y * KCHUNK;
    int tid = threadIdx.x;
    int w = tid >> 6, lane = tid & 63;
    int col = lane & 15, quad = lane >> 4;
    floatx4 acc[4] = {};
    for (int step = 0; step < 17; step++) {
        int kb = kb0 + step * 64;
        __syncthreads();
        #pragma unroll
        for (int l = 0; l < 2; l++) {
            int slot = tid + l * 256;
            int row = slot >> 3, grp = slot & 7;
            uint4 da = *(const uint4*)(yT + (size_t)(i0 + row) * KTOT + kb + grp * 8);
            *(uint4*)(&As[row * 72 + grp * 8]) = da;
            uint4 db = *(const uint4*)(yT + (size_t)(j0 + row) * KTOT + kb + grp * 8);
            *(uint4*)(&Bs[row * 72 + grp * 8]) = db;
        }
        __syncthreads();
        #pragma unroll
        for (int sub = 0; sub < 2; sub++) {
            short8 a = *(const short8*)(&As[(w * 16 + col) * 72 + sub * 32 + quad * 8]);
            #pragma unroll
            for (int jt = 0; jt < 4; jt++) {
                short8 b = *(const short8*)(&Bs[(jt * 16 + col) * 72 + sub * 32 + quad * 8]);
                acc[jt] = __builtin_amdgcn_mfma_f32_16x16x32_bf16(a, b, acc[jt], 0, 0, 0);
            }
        }
    }
    bool offDiag = (i0 != j0);
    #pragma unroll
    for (int jt = 0; jt < 4; jt++)
        #pragma unroll
        for (int r = 0; r < 4; r++) {
            int gi = i0 + w * 16 + quad * 4 + r;
            int gj = j0 + jt * 16 + col;
            float val = acc[jt][r];
            atomicAdd(&g[(size_t)gi * C + gj], val);
            if (offDiag) atomicAdd(&g[(size_t)gj * C + gi], val);
        }
}

__global__ __launch_bounds__(256) void out_kernel(const float* __restrict__ g,
                                                  const float* __restrict__ lin_w,
                                                  const float* __restrict__ lin_b,
                                                  float* __restrict__ out) {
    __shared__ float gs[C];
    int i = blockIdx.x, j = threadIdx.x;
    gs[j] = g[(size_t)i * C + j];
    __syncthreads();
    float acc = lin_b[j];
    const float* wrow = lin_w + (size_t)j * C;
    for (int k = 0; k < C; k++) acc += gs[k] * wrow[k];
    out[(size_t)i * C + j] = (acc > 0.f) ? acc : SLOPE * acc;
}

extern "C" void kernel_launch(void* const* d_in, const int* in_sizes, int n_in,
                              void* d_out, int out_size, void* d_ws, size_t ws_size,
                              hipStream_t stream) {
    const float* emb    = (const float*)d_in[0];
    const float* conv_w = (const float*)d_in[1];
    const float* conv_b = (const float*)d_in[2];
    const float* lin_w  = (const float*)d_in[3];
    const float* lin_b  = (const float*)d_in[4];
    const int*   eidx   = (const int*)d_in[5];
    const int* node_idx = eidx;        // edge_index[0]
    const int* edge_idx = eidx + NNZ;  // edge_index[1]

    char* ws = (char*)d_ws;
    int* cc_e  = (int*)(ws + OFF_CC_E);
    int* cc_n  = (int*)(ws + OFF_CC_N);
    int* cur_e = (int*)(ws + OFF_CUR_E);
    int* cur_n = (int*)(ws + OFF_CUR_N);
    float* g   = (float*)(ws + OFF_G);
    int* cb_e  = (int*)(ws + OFF_CB_E);
    int* cb_n  = (int*)(ws + OFF_CB_N);
    int* rs_n  = (int*)(ws + OFF_RS_N);
    int* rs_e  = (int*)(ws + OFF_RS_E);
    int* buf_e = (int*)(ws + OFF_BUF_E);
    int* buf_n = (int*)(ws + OFF_BUF_N);
    int* csr_e = (int*)(ws + OFF_CSR_E);
    int* csr_n = (int*)(ws + OFF_CSR_N);
    uint4* embh4 = (uint4*)(ws + OFF_EMBH);
    unsigned short* e_acc_h = (unsigned short*)(ws + OFF_EACC);
    unsigned short* e2h = (unsigned short*)(ws + OFF_E2);
    unsigned short* cwh = (unsigned short*)(ws + OFF_CWH);
    unsigned short* yT  = (unsigned short*)(ws + OFF_YT);
    float* out = (float*)d_out;

    int n4 = ZERO_BYTES / 16;
    zero_kernel<<<(n4 + 255) / 256, 256, 0, stream>>>((float4*)ws, n4);

    cast_bf16_kernel<<<6250, 256, 0, stream>>>((const float4*)emb, embh4, 1600000);
    cast_bf16_kernel<<<32, 256, 0, stream>>>((const float4*)conv_w, (uint4*)cwh, 8192);

    coarse_count_kernel<<<256, 256, 0, stream>>>(node_idx, edge_idx, cc_e, cc_n);

    coarse_scan_kernel<<<1, 256, 0, stream>>>(cc_e, cc_n, cb_e, cb_n);

    bucket_scatter_kernel<<<256, 256, 0, stream>>>(node_idx, edge_idx, cb_e, cb_n,
                                                   cur_e, cur_n, buf_e, buf_n);

    bucket_sort_kernel<<<2 * NB, 256, 0, stream>>>(buf_e, buf_n, cb_e, cb_n,
                                                   csr_e, csr_n, rs_e, rs_n);

    edge_aggregate_kernel<<<MPAD / 4, 256, 0, stream>>>(embh4, csr_e, rs_e, e_acc_h);

    edge_gemm_mfma_kernel<<<dim3(MPAD / 64, C / 64), 256, 0, stream>>>(e_acc_h, cwh, rs_e, e2h);

    node_aggregate_t_kernel<<<KTOT / 32, 256, 0, stream>>>((const uint4*)e2h, csr_n, rs_n,
                                                           conv_b, yT);

    gram_mfma_kernel<<<dim3(10, NZB), 256, 0, stream>>>(yT, g);

    out_kernel<<<C, 256, 0, stream>>>(g, lin_w, lin_b, out);
}

// Round 9
// 318.034 us; speedup vs baseline: 1.0542x; 1.0542x over previous
//
#include <hip/hip_runtime.h>

#define N_NODES 50000
#define N_EDGES 10000
#define NNZ     800000
#define C       256
#define SLOPE   0.01f
#define KTOT    50048   // node count padded to multiple of 64
#define KCHUNK  1088    // 17 * 64
#define NZB     46      // KTOT / KCHUNK
#define MPAD    10048   // edge count padded to multiple of 64

#define NB      250     // coarse buckets per side
#define EB_E    40      // edges per bucket   (250*40  = 10000)
#define EB_N    200     // nodes per bucket   (250*200 = 50000)
#define CHUNK   3125    // NNZ / 256 blocks
#define CAP     6000    // LDS item capacity in bucket_sort (mean 3200, sd ~57)

// ---- workspace layout (bytes) ----
#define OFF_CC_E    0          // 250*4 coarse counts (edge)
#define OFF_CC_N    1024       // 250*4 coarse counts (node)
#define OFF_CUR_E   2048       // 250*4 scatter cursors
#define OFF_CUR_N   3072       // 250*4
#define OFF_G       4096       // 256*256*4
#define ZERO_BYTES  266240     // zero region [0, ZERO_BYTES), /16 ok
#define OFF_CB_E    266240     // 251*4 coarse bases (edge)
#define OFF_CB_N    267264     // 251*4 coarse bases (node)
#define OFF_RS_N    268288     // 50001*4 (written by bucket_sort)
#define OFF_RS_E    468480     // 10001*4 (written by bucket_sort)
#define OFF_BUF_E   508672     // 800000*4 bucketed items (edge side)
#define OFF_BUF_N   3708672    // 800000*4 bucketed items (node side)
#define OFF_CSR_E   6908672    // 800000*4 node ids grouped by edge
#define OFF_CSR_N   10108672   // 800000*4 edge ids grouped by node
#define OFF_EMBH    13308672   // 50001*256*2 bf16 incl zero-sentinel row 50000
#define OFF_YT      13308672   // 256*50048*2 bf16 — ALIASES embh (embh dead first);
                               // ends at 38,933,248 (== OFF_EACC, no overlap)
#define OFF_EACC    38933248   // 10048*256*2 bf16 (dead after edge_gemm)
#define OFF_E2      44077824   // 10048*256*2 bf16; rows 10000.. are ZERO (sentinel)
#define OFF_CWH     49222400   // 256*256*2 bf16 conv_w  -> end 49,353,472

typedef __attribute__((ext_vector_type(8))) short short8;
typedef __attribute__((ext_vector_type(4))) float floatx4;

static __device__ __forceinline__ unsigned short f2bf(float f) {
    unsigned int u = __float_as_uint(f);
    u = (u + 0x7fffu + ((u >> 16) & 1u)) >> 16;   // RNE
    return (unsigned short)u;
}

// unpack uint4 (8 bf16) and accumulate into a[0..7]
static __device__ __forceinline__ void acc_bf8(const uint4 d, float* a) {
    a[0] += __uint_as_float(d.x << 16);
    a[1] += __uint_as_float(d.x & 0xffff0000u);
    a[2] += __uint_as_float(d.y << 16);
    a[3] += __uint_as_float(d.y & 0xffff0000u);
    a[4] += __uint_as_float(d.z << 16);
    a[5] += __uint_as_float(d.z & 0xffff0000u);
    a[6] += __uint_as_float(d.w << 16);
    a[7] += __uint_as_float(d.w & 0xffff0000u);
}

// Masked 4-deep gather: rows csr[s+half], csr[s+half+2], ... < t; OOB slots
// clamped to the zero-sentinel row `zrow` (adds 0). Always 4 loads in flight —
// no serial tail even at low degree (mean node degree = 8 items/half-wave).
static __device__ __forceinline__ void gather4(const uint4* __restrict__ tbl4,
                                               const int* __restrict__ csr,
                                               int s, int t, int half, int l32,
                                               int zrow, float* a) {
    for (int i = s + half; i < t; i += 8) {
        int e0 = csr[i];
        int e1 = (i + 2 < t) ? csr[i + 2] : zrow;
        int e2 = (i + 4 < t) ? csr[i + 4] : zrow;
        int e3 = (i + 6 < t) ? csr[i + 6] : zrow;
        uint4 d0 = tbl4[(size_t)e0 * 32 + l32];
        uint4 d1 = tbl4[(size_t)e1 * 32 + l32];
        uint4 d2 = tbl4[(size_t)e2 * 32 + l32];
        uint4 d3 = tbl4[(size_t)e3 * 32 + l32];
        acc_bf8(d0, a); acc_bf8(d1, a); acc_bf8(d2, a); acc_bf8(d3, a);
    }
}

// Masked 8-deep gather (edge side: mean 40 items/half-wave)
static __device__ __forceinline__ void gather8(const uint4* __restrict__ tbl4,
                                               const int* __restrict__ csr,
                                               int s, int t, int half, int l32,
                                               int zrow, float* a) {
    for (int i = s + half; i < t; i += 16) {
        int e0 = csr[i];
        int e1 = (i + 2  < t) ? csr[i + 2]  : zrow;
        int e2 = (i + 4  < t) ? csr[i + 4]  : zrow;
        int e3 = (i + 6  < t) ? csr[i + 6]  : zrow;
        int e4 = (i + 8  < t) ? csr[i + 8]  : zrow;
        int e5 = (i + 10 < t) ? csr[i + 10] : zrow;
        int e6 = (i + 12 < t) ? csr[i + 12] : zrow;
        int e7 = (i + 14 < t) ? csr[i + 14] : zrow;
        uint4 d0 = tbl4[(size_t)e0 * 32 + l32];
        uint4 d1 = tbl4[(size_t)e1 * 32 + l32];
        uint4 d2 = tbl4[(size_t)e2 * 32 + l32];
        uint4 d3 = tbl4[(size_t)e3 * 32 + l32];
        uint4 d4 = tbl4[(size_t)e4 * 32 + l32];
        uint4 d5 = tbl4[(size_t)e5 * 32 + l32];
        uint4 d6 = tbl4[(size_t)e6 * 32 + l32];
        uint4 d7 = tbl4[(size_t)e7 * 32 + l32];
        acc_bf8(d0, a); acc_bf8(d1, a); acc_bf8(d2, a); acc_bf8(d3, a);
        acc_bf8(d4, a); acc_bf8(d5, a); acc_bf8(d6, a); acc_bf8(d7, a);
    }
}

__global__ __launch_bounds__(256) void zero_kernel(float4* __restrict__ p, int n4) {
    int i = blockIdx.x * 256 + threadIdx.x;
    if (i < n4) p[i] = make_float4(0.f, 0.f, 0.f, 0.f);
}

// f32 -> bf16 cast (8 elems/thread); slots [src_n8, n8) are zero-filled
// (used to create the zero-sentinel row at the end of embh)
__global__ __launch_bounds__(256) void cast_bf16_kernel(const float4* __restrict__ src4,
                                                        uint4* __restrict__ dst4,
                                                        int src_n8, int n8) {
    int i = blockIdx.x * 256 + threadIdx.x;
    if (i >= n8) return;
    uint4 o = {0u, 0u, 0u, 0u};
    if (i < src_n8) {
        float4 f0 = src4[2 * i], f1 = src4[2 * i + 1];
        o.x = f2bf(f0.x) | ((unsigned)f2bf(f0.y) << 16);
        o.y = f2bf(f0.z) | ((unsigned)f2bf(f0.w) << 16);
        o.z = f2bf(f1.x) | ((unsigned)f2bf(f1.y) << 16);
        o.w = f2bf(f1.z) | ((unsigned)f2bf(f1.w) << 16);
    }
    dst4[i] = o;
}

// coarse histogram: per-block LDS hist over 250 buckets/side, then one global
// atomic per (block,bucket)
__global__ __launch_bounds__(256) void coarse_count_kernel(const int* __restrict__ node_idx,
                                                           const int* __restrict__ edge_idx,
                                                           int* __restrict__ cc_e,
                                                           int* __restrict__ cc_n) {
    __shared__ int he[NB], hn[NB];
    int tid = threadIdx.x;
    int base = blockIdx.x * CHUNK;
    for (int i = tid; i < NB; i += 256) { he[i] = 0; hn[i] = 0; }
    __syncthreads();
    for (int i = tid; i < CHUNK; i += 256) {
        atomicAdd(&he[edge_idx[base + i] / EB_E], 1);
        atomicAdd(&hn[node_idx[base + i] / EB_N], 1);
    }
    __syncthreads();
    for (int k = tid; k < NB; k += 256) {
        if (he[k]) atomicAdd(&cc_e[k], he[k]);
        if (hn[k]) atomicAdd(&cc_n[k], hn[k]);
    }
}

// single-block exclusive scan of both coarse-count arrays -> coarse bases
__global__ __launch_bounds__(256) void coarse_scan_kernel(const int* __restrict__ cc_e,
                                                          const int* __restrict__ cc_n,
                                                          int* __restrict__ cb_e,
                                                          int* __restrict__ cb_n) {
    __shared__ int tmp[256];
    int tid = threadIdx.x;
    int v = (tid < NB) ? cc_e[tid] : 0;
    tmp[tid] = v;
    __syncthreads();
    for (int off = 1; off < 256; off <<= 1) {
        int t = (tid >= off) ? tmp[tid - off] : 0;
        __syncthreads();
        tmp[tid] += t;
        __syncthreads();
    }
    if (tid < NB) cb_e[tid + 1] = tmp[tid];
    if (tid == 0) cb_e[0] = 0;
    __syncthreads();
    v = (tid < NB) ? cc_n[tid] : 0;
    tmp[tid] = v;
    __syncthreads();
    for (int off = 1; off < 256; off <<= 1) {
        int t = (tid >= off) ? tmp[tid - off] : 0;
        __syncthreads();
        tmp[tid] += t;
        __syncthreads();
    }
    if (tid < NB) cb_n[tid + 1] = tmp[tid];
    if (tid == 0) cb_n[0] = 0;
}

// pass 1: scatter incidences into coarse buckets (both sides), line-dense writes
__global__ __launch_bounds__(256) void bucket_scatter_kernel(const int* __restrict__ node_idx,
                                                             const int* __restrict__ edge_idx,
                                                             const int* __restrict__ cb_e,
                                                             const int* __restrict__ cb_n,
                                                             int* __restrict__ cur_e,
                                                             int* __restrict__ cur_n,
                                                             int* __restrict__ buf_e,
                                                             int* __restrict__ buf_n) {
    __shared__ int he[NB], hn[NB], be[NB], bn[NB];
    int tid = threadIdx.x;
    int base = blockIdx.x * CHUNK;
    for (int i = tid; i < NB; i += 256) { he[i] = 0; hn[i] = 0; }
    __syncthreads();
    for (int i = tid; i < CHUNK; i += 256) {
        int e = edge_idx[base + i], v = node_idx[base + i];
        atomicAdd(&he[e / EB_E], 1);
        atomicAdd(&hn[v / EB_N], 1);
    }
    __syncthreads();
    for (int k = tid; k < NB; k += 256) {
        int c = he[k];
        be[k] = cb_e[k] + (c ? atomicAdd(&cur_e[k], c) : 0);
        int cn = hn[k];
        bn[k] = cb_n[k] + (cn ? atomicAdd(&cur_n[k], cn) : 0);
    }
    __syncthreads();
    for (int i = tid; i < NB; i += 256) { he[i] = 0; hn[i] = 0; }
    __syncthreads();
    for (int i = tid; i < CHUNK; i += 256) {
        int e = edge_idx[base + i], v = node_idx[base + i];
        int ke = e / EB_E, kn = v / EB_N;
        int oe = atomicAdd(&he[ke], 1);
        buf_e[be[ke] + oe] = (v << 6) | (e - ke * EB_E);
        int on = atomicAdd(&hn[kn], 1);
        buf_n[bn[kn] + on] = (e << 8) | (v - kn * EB_N);
    }
}

// pass 2: per-bucket LDS counting sort -> final CSR + emit fine rs
__global__ __launch_bounds__(256) void bucket_sort_kernel(const int* __restrict__ buf_e,
                                                          const int* __restrict__ buf_n,
                                                          const int* __restrict__ cb_e,
                                                          const int* __restrict__ cb_n,
                                                          int* __restrict__ csr_e,
                                                          int* __restrict__ csr_n,
                                                          int* __restrict__ rs_e,
                                                          int* __restrict__ rs_n) {
    __shared__ int A[CAP];
    __shared__ int h[EB_N], bs[EB_N];
    int tid = threadIdx.x;
    bool edgeSide = blockIdx.x < NB;
    int k = edgeSide ? blockIdx.x : blockIdx.x - NB;
    int eb = edgeSide ? EB_E : EB_N;
    int shift = edgeSide ? 6 : 8;
    int mask = (1 << shift) - 1;
    const int* cb  = edgeSide ? cb_e : cb_n;
    const int* buf = edgeSide ? buf_e : buf_n;
    int* csr       = edgeSide ? csr_e : csr_n;
    int* rs        = edgeSide ? rs_e : rs_n;
    int base = cb[k];
    int cnt = cb[k + 1] - base;
    for (int i = tid; i < eb; i += 256) h[i] = 0;
    __syncthreads();
    for (int i = tid; i < cnt; i += 256) {
        int it = buf[base + i];
        if (i < CAP) A[i] = it;
        atomicAdd(&h[it & mask], 1);
    }
    __syncthreads();
    if (tid == 0) {
        int s = 0;
        for (int j = 0; j < eb; j++) { bs[j] = s; s += h[j]; }
    }
    __syncthreads();
    for (int j = tid; j < eb; j += 256) {
        rs[k * eb + j] = base + bs[j];
        h[j] = 0;
    }
    if (tid == 0 && k == NB - 1) rs[edgeSide ? N_EDGES : N_NODES] = NNZ;
    __syncthreads();
    for (int i = tid; i < cnt; i += 256) {
        int it = (i < CAP) ? A[i] : buf[base + i];
        int loc = it & mask;
        int off = bs[loc] + atomicAdd(&h[loc], 1);
        csr[base + off] = it >> shift;
    }
}

// one wave per hyperedge; masked 8-deep gathers; bf16 output (pad rows zeroed)
__global__ __launch_bounds__(256) void edge_aggregate_kernel(const uint4* __restrict__ embh4,
                                                             const int* __restrict__ csr_e,
                                                             const int* __restrict__ rs_e,
                                                             unsigned short* __restrict__ e_acc_h) {
    int e = blockIdx.x * 4 + (threadIdx.x >> 6);
    int lane = threadIdx.x & 63;
    int half = lane >> 5, l32 = lane & 31;
    int s = 0, t = 0;
    if (e < N_EDGES) { s = rs_e[e]; t = rs_e[e + 1]; }
    float a[8] = {0.f, 0.f, 0.f, 0.f, 0.f, 0.f, 0.f, 0.f};
    gather8(embh4, csr_e, s, t, half, l32, N_NODES, a);
    #pragma unroll
    for (int j = 0; j < 8; j++) a[j] += __shfl_xor(a[j], 32);
    if (half == 0) {
        uint4 o;
        o.x = f2bf(a[0]) | ((unsigned)f2bf(a[1]) << 16);
        o.y = f2bf(a[2]) | ((unsigned)f2bf(a[3]) << 16);
        o.z = f2bf(a[4]) | ((unsigned)f2bf(a[5]) << 16);
        o.w = f2bf(a[6]) | ((unsigned)f2bf(a[7]) << 16);
        ((uint4*)(e_acc_h + (size_t)e * C))[l32] = o;
    }
}

// e2[m][n] = Binv[m] * sum_k e_acc[m][k] * conv_w[n][k] via MFMA; grid (157,4)
// pad rows (m >= N_EDGES) stored as ZERO -> e2h row N_EDGES is the sentinel
__global__ __launch_bounds__(256) void edge_gemm_mfma_kernel(const unsigned short* __restrict__ e_acc_h,
                                                             const unsigned short* __restrict__ cwh,
                                                             const int* __restrict__ rs_e,
                                                             unsigned short* __restrict__ e2h) {
    __shared__ __align__(16) unsigned short As[64 * 72];
    __shared__ __align__(16) unsigned short Bs[64 * 72];
    int i0 = blockIdx.x * 64, j0 = blockIdx.y * 64;
    int tid = threadIdx.x;
    int w = tid >> 6, lane = tid & 63;
    int col = lane & 15, quad = lane >> 4;
    floatx4 acc[4] = {};
    for (int step = 0; step < 4; step++) {
        int kb = step * 64;
        __syncthreads();
        #pragma unroll
        for (int l = 0; l < 2; l++) {
            int slot = tid + l * 256;
            int row = slot >> 3, grp = slot & 7;
            uint4 da = *(const uint4*)(e_acc_h + (size_t)(i0 + row) * C + kb + grp * 8);
            *(uint4*)(&As[row * 72 + grp * 8]) = da;
            uint4 db = *(const uint4*)(cwh + (size_t)(j0 + row) * C + kb + grp * 8);
            *(uint4*)(&Bs[row * 72 + grp * 8]) = db;
        }
        __syncthreads();
        #pragma unroll
        for (int sub = 0; sub < 2; sub++) {
            short8 a = *(const short8*)(&As[(w * 16 + col) * 72 + sub * 32 + quad * 8]);
            #pragma unroll
            for (int jt = 0; jt < 4; jt++) {
                short8 b = *(const short8*)(&Bs[(jt * 16 + col) * 72 + sub * 32 + quad * 8]);
                acc[jt] = __builtin_amdgcn_mfma_f32_16x16x32_bf16(a, b, acc[jt], 0, 0, 0);
            }
        }
    }
    #pragma unroll
    for (int r = 0; r < 4; r++) {
        int m = i0 + w * 16 + quad * 4 + r;          // < MPAD always
        int deg = (m < N_EDGES) ? rs_e[m + 1] - rs_e[m] : 0;
        float binv = (deg > 0) ? 1.0f / (float)deg : 0.0f;
        #pragma unroll
        for (int jt = 0; jt < 4; jt++)
            e2h[(size_t)m * C + j0 + jt * 16 + col] = f2bf(acc[jt][r] * binv);
    }
}

// 32 nodes per block (4 waves x 8 nodes); masked 4-deep gathers; fused
// Dinv/bias/lrelu; write yT (transposed via LDS)
__global__ __launch_bounds__(256) void node_aggregate_t_kernel(const uint4* __restrict__ e2h4,
                                                               const int* __restrict__ csr_n,
                                                               const int* __restrict__ rs_n,
                                                               const float* __restrict__ conv_b,
                                                               unsigned short* __restrict__ yT) {
    __shared__ __align__(16) unsigned short T[32][256];  // [node][ch]
    int n0 = blockIdx.x * 32;
    int tid = threadIdx.x;
    int w = tid >> 6, lane = tid & 63;
    int half = lane >> 5, l32 = lane & 31;
    int base = n0 + w * 8;
    // __shfl below runs with ALL 64 lanes active (uniform q loop) — safe
    int rsv = rs_n[min(base + lane, N_NODES)];
    float4 b0 = ((const float4*)conv_b)[l32 * 2];
    float4 b1 = ((const float4*)conv_b)[l32 * 2 + 1];
    float bb[8] = {b0.x, b0.y, b0.z, b0.w, b1.x, b1.y, b1.z, b1.w};
    for (int q = 0; q < 8; q++) {
        int v = base + q;
        int s = __shfl(rsv, q), t = __shfl(rsv, q + 1);
        float a[8] = {0.f, 0.f, 0.f, 0.f, 0.f, 0.f, 0.f, 0.f};
        gather4(e2h4, csr_n, s, t, half, l32, N_EDGES, a);
        #pragma unroll
        for (int j = 0; j < 8; j++) a[j] += __shfl_xor(a[j], 32);
        float dinv = (t > s) ? 1.0f / (float)(t - s) : 0.0f;
        unsigned int pk[4];
        #pragma unroll
        for (int j = 0; j < 4; j++) {
            float r0 = a[2 * j] * dinv + bb[2 * j];
            float r1 = a[2 * j + 1] * dinv + bb[2 * j + 1];
            r0 = (r0 > 0.f) ? r0 : SLOPE * r0;
            r1 = (r1 > 0.f) ? r1 : SLOPE * r1;
            if (v >= N_NODES) { r0 = 0.f; r1 = 0.f; }   // zero-pad rows
            pk[j] = f2bf(r0) | ((unsigned)f2bf(r1) << 16);
        }
        if (half == 0) {
            uint4 o; o.x = pk[0]; o.y = pk[1]; o.z = pk[2]; o.w = pk[3];
            *(uint4*)(&T[w * 8 + q][l32 * 8]) = o;
        }
    }
    __syncthreads();
    int ch = tid;
    #pragma unroll
    for (int jj = 0; jj < 4; jj++) {
        uint4 o;
        o.x = T[jj * 8 + 0][ch] | ((unsigned)T[jj * 8 + 1][ch] << 16);
        o.y = T[jj * 8 + 2][ch] | ((unsigned)T[jj * 8 + 3][ch] << 16);
        o.z = T[jj * 8 + 4][ch] | ((unsigned)T[jj * 8 + 5][ch] << 16);
        o.w = T[jj * 8 + 6][ch] | ((unsigned)T[jj * 8 + 7][ch] << 16);
        *(uint4*)(yT + (size_t)ch * KTOT + n0 + jj * 8) = o;
    }
}

// g += yT-tile^T yT-tile via MFMA, SYMMETRY-aware: only 10 upper-tri tile
// pairs computed; off-diagonal results mirrored. grid (10, NZB)
__global__ __launch_bounds__(256) void gram_mfma_kernel(const unsigned short* __restrict__ yT,
                                                        float* __restrict__ g) {
    static const int PI[10] = {0, 0, 0, 0, 1, 1, 1, 2, 2, 3};
    static const int PJ[10] = {0, 1, 2, 3, 1, 2, 3, 2, 3, 3};
    __shared__ __align__(16) unsigned short As[64 * 72];  // [col][k], stride 72
    __shared__ __align__(16) unsigned short Bs[64 * 72];
    int i0 = PI[blockIdx.x] * 64, j0 = PJ[blockIdx.x] * 64;
    int kb0 = blockIdx.y * KCHUNK;
    int tid = threadIdx.x;
    int w = tid >> 6, lane = tid & 63;
    int col = lane & 15, quad = lane >> 4;
    floatx4 acc[4] = {};
    for (int step = 0; step < 17; step++) {
        int kb = kb0 + step * 64;
        __syncthreads();
        #pragma unroll
        for (int l = 0; l < 2; l++) {
            int slot = tid + l * 256;
            int row = slot >> 3, grp = slot & 7;
            uint4 da = *(const uint4*)(yT + (size_t)(i0 + row) * KTOT + kb + grp * 8);
            *(uint4*)(&As[row * 72 + grp * 8]) = da;
            uint4 db = *(const uint4*)(yT + (size_t)(j0 + row) * KTOT + kb + grp * 8);
            *(uint4*)(&Bs[row * 72 + grp * 8]) = db;
        }
        __syncthreads();
        #pragma unroll
        for (int sub = 0; sub < 2; sub++) {
            short8 a = *(const short8*)(&As[(w * 16 + col) * 72 + sub * 32 + quad * 8]);
            #pragma unroll
            for (int jt = 0; jt < 4; jt++) {
                short8 b = *(const short8*)(&Bs[(jt * 16 + col) * 72 + sub * 32 + quad * 8]);
                acc[jt] = __builtin_amdgcn_mfma_f32_16x16x32_bf16(a, b, acc[jt], 0, 0, 0);
            }
        }
    }
    bool offDiag = (i0 != j0);
    #pragma unroll
    for (int jt = 0; jt < 4; jt++)
        #pragma unroll
        for (int r = 0; r < 4; r++) {
            int gi = i0 + w * 16 + quad * 4 + r;
            int gj = j0 + jt * 16 + col;
            float val = acc[jt][r];
            atomicAdd(&g[(size_t)gi * C + gj], val);
            if (offDiag) atomicAdd(&g[(size_t)gj * C + gi], val);
        }
}

__global__ __launch_bounds__(256) void out_kernel(const float* __restrict__ g,
                                                  const float* __restrict__ lin_w,
                                                  const float* __restrict__ lin_b,
                                                  float* __restrict__ out) {
    __shared__ float gs[C];
    int i = blockIdx.x, j = threadIdx.x;
    gs[j] = g[(size_t)i * C + j];
    __syncthreads();
    float acc = lin_b[j];
    const float* wrow = lin_w + (size_t)j * C;
    for (int k = 0; k < C; k++) acc += gs[k] * wrow[k];
    out[(size_t)i * C + j] = (acc > 0.f) ? acc : SLOPE * acc;
}

extern "C" void kernel_launch(void* const* d_in, const int* in_sizes, int n_in,
                              void* d_out, int out_size, void* d_ws, size_t ws_size,
                              hipStream_t stream) {
    const float* emb    = (const float*)d_in[0];
    const float* conv_w = (const float*)d_in[1];
    const float* conv_b = (const float*)d_in[2];
    const float* lin_w  = (const float*)d_in[3];
    const float* lin_b  = (const float*)d_in[4];
    const int*   eidx   = (const int*)d_in[5];
    const int* node_idx = eidx;        // edge_index[0]
    const int* edge_idx = eidx + NNZ;  // edge_index[1]

    char* ws = (char*)d_ws;
    int* cc_e  = (int*)(ws + OFF_CC_E);
    int* cc_n  = (int*)(ws + OFF_CC_N);
    int* cur_e = (int*)(ws + OFF_CUR_E);
    int* cur_n = (int*)(ws + OFF_CUR_N);
    float* g   = (float*)(ws + OFF_G);
    int* cb_e  = (int*)(ws + OFF_CB_E);
    int* cb_n  = (int*)(ws + OFF_CB_N);
    int* rs_n  = (int*)(ws + OFF_RS_N);
    int* rs_e  = (int*)(ws + OFF_RS_E);
    int* buf_e = (int*)(ws + OFF_BUF_E);
    int* buf_n = (int*)(ws + OFF_BUF_N);
    int* csr_e = (int*)(ws + OFF_CSR_E);
    int* csr_n = (int*)(ws + OFF_CSR_N);
    uint4* embh4 = (uint4*)(ws + OFF_EMBH);
    unsigned short* e_acc_h = (unsigned short*)(ws + OFF_EACC);
    unsigned short* e2h = (unsigned short*)(ws + OFF_E2);
    unsigned short* cwh = (unsigned short*)(ws + OFF_CWH);
    unsigned short* yT  = (unsigned short*)(ws + OFF_YT);
    float* out = (float*)d_out;

    int n4 = ZERO_BYTES / 16;
    zero_kernel<<<(n4 + 255) / 256, 256, 0, stream>>>((float4*)ws, n4);

    // emb -> bf16 + zero-sentinel row at index N_NODES (slots 1,600,000..1,600,031)
    cast_bf16_kernel<<<6251, 256, 0, stream>>>((const float4*)emb, embh4, 1600000, 1600032);
    cast_bf16_kernel<<<32, 256, 0, stream>>>((const float4*)conv_w, (uint4*)cwh, 8192, 8192);

    coarse_count_kernel<<<256, 256, 0, stream>>>(node_idx, edge_idx, cc_e, cc_n);

    coarse_scan_kernel<<<1, 256, 0, stream>>>(cc_e, cc_n, cb_e, cb_n);

    bucket_scatter_kernel<<<256, 256, 0, stream>>>(node_idx, edge_idx, cb_e, cb_n,
                                                   cur_e, cur_n, buf_e, buf_n);

    bucket_sort_kernel<<<2 * NB, 256, 0, stream>>>(buf_e, buf_n, cb_e, cb_n,
                                                   csr_e, csr_n, rs_e, rs_n);

    edge_aggregate_kernel<<<MPAD / 4, 256, 0, stream>>>(embh4, csr_e, rs_e, e_acc_h);

    edge_gemm_mfma_kernel<<<dim3(MPAD / 64, C / 64), 256, 0, stream>>>(e_acc_h, cwh, rs_e, e2h);

    node_aggregate_t_kernel<<<KTOT / 32, 256, 0, stream>>>((const uint4*)e2h, csr_n, rs_n,
                                                           conv_b, yT);

    gram_mfma_kernel<<<dim3(10, NZB), 256, 0, stream>>>(yT, g);

    out_kernel<<<C, 256, 0, stream>>>(g, lin_w, lin_b, out);
}

// Round 10
// 307.088 us; speedup vs baseline: 1.0918x; 1.0356x over previous
//
#include <hip/hip_runtime.h>

#define N_NODES 50000
#define N_EDGES 10000
#define NNZ     800000
#define C       256
#define SLOPE   0.01f
#define KTOT    50176   // node count padded to 512*98
#define KCHUNK  512     // 8 * 64
#define NZB     98      // KTOT / KCHUNK
#define MPAD    10048   // edge count padded to multiple of 64

#define NB      250     // coarse buckets per side
#define EB_E    40      // edges per bucket   (250*40  = 10000)
#define EB_N    200     // nodes per bucket   (250*200 = 50000)
#define CHUNK   3125    // NNZ / 256 blocks
#define CAP     6000    // LDS item capacity in bucket_sort (mean 3200, sd ~57)

// ---- workspace layout (bytes) ----
#define OFF_CC_E    0          // 250*4 coarse counts (edge)
#define OFF_CC_N    1024       // 250*4 coarse counts (node)
#define OFF_CUR_E   2048       // 250*4 scatter cursors
#define OFF_CUR_N   3072       // 250*4
#define ZERO_BYTES  4096       // zero region: counters only
#define OFF_G       4096       // 256*256*4 (fully written by greduce)
#define OFF_CB_E    266240     // 251*4 coarse bases (edge)
#define OFF_CB_N    267264     // 251*4 coarse bases (node)
#define OFF_RS_N    268288     // 50001*4 (written by bucket_sort)
#define OFF_RS_E    468480     // 10001*4 (written by bucket_sort)
#define OFF_BUF_E   508672     // 800000*4 bucketed items (edge side)
#define OFF_BUF_N   3708672    // 800000*4 bucketed items (node side)
#define OFF_CSR_E   6908672    // 800000*4 node ids grouped by edge
#define OFF_CSR_N   10108672   // 800000*4 edge ids grouped by node
#define OFF_EMBH    13308672   // 50001*256*2 bf16 incl zero-sentinel row 50000
#define OFF_YT      13308672   // 256*50176*2 bf16 — ALIASES embh (embh dead before
                               // node_aggregate writes yT); ends 38,998,784
#define OFF_EACC    39000064   // 10048*256*2 bf16 (dead after edge_gemm)
#define OFF_E2      44144640   // 10048*256*2 bf16; rows 10000.. ZERO (sentinel)
#define OFF_CWH     49289216   // 256*256*2 bf16 conv_w
#define OFF_PART    49420288   // 98*10*4096*4 gram partials -> end 65,476,608

typedef __attribute__((ext_vector_type(8))) short short8;
typedef __attribute__((ext_vector_type(4))) float floatx4;

static __device__ __forceinline__ unsigned short f2bf(float f) {
    unsigned int u = __float_as_uint(f);
    u = (u + 0x7fffu + ((u >> 16) & 1u)) >> 16;   // RNE
    return (unsigned short)u;
}

// unpack uint4 (8 bf16) and accumulate into a[0..7]
static __device__ __forceinline__ void acc_bf8(const uint4 d, float* a) {
    a[0] += __uint_as_float(d.x << 16);
    a[1] += __uint_as_float(d.x & 0xffff0000u);
    a[2] += __uint_as_float(d.y << 16);
    a[3] += __uint_as_float(d.y & 0xffff0000u);
    a[4] += __uint_as_float(d.z << 16);
    a[5] += __uint_as_float(d.z & 0xffff0000u);
    a[6] += __uint_as_float(d.w << 16);
    a[7] += __uint_as_float(d.w & 0xffff0000u);
}

// Masked 4-deep gather: rows csr[s+half], csr[s+half+2], ... < t; OOB slots
// clamped to the zero-sentinel row `zrow` (adds 0). Always 4 loads in flight.
static __device__ __forceinline__ void gather4(const uint4* __restrict__ tbl4,
                                               const int* __restrict__ csr,
                                               int s, int t, int half, int l32,
                                               int zrow, float* a) {
    for (int i = s + half; i < t; i += 8) {
        int e0 = csr[i];
        int e1 = (i + 2 < t) ? csr[i + 2] : zrow;
        int e2 = (i + 4 < t) ? csr[i + 4] : zrow;
        int e3 = (i + 6 < t) ? csr[i + 6] : zrow;
        uint4 d0 = tbl4[(size_t)e0 * 32 + l32];
        uint4 d1 = tbl4[(size_t)e1 * 32 + l32];
        uint4 d2 = tbl4[(size_t)e2 * 32 + l32];
        uint4 d3 = tbl4[(size_t)e3 * 32 + l32];
        acc_bf8(d0, a); acc_bf8(d1, a); acc_bf8(d2, a); acc_bf8(d3, a);
    }
}

// Masked 8-deep gather (edge side: mean 40 items/half-wave)
static __device__ __forceinline__ void gather8(const uint4* __restrict__ tbl4,
                                               const int* __restrict__ csr,
                                               int s, int t, int half, int l32,
                                               int zrow, float* a) {
    for (int i = s + half; i < t; i += 16) {
        int e0 = csr[i];
        int e1 = (i + 2  < t) ? csr[i + 2]  : zrow;
        int e2 = (i + 4  < t) ? csr[i + 4]  : zrow;
        int e3 = (i + 6  < t) ? csr[i + 6]  : zrow;
        int e4 = (i + 8  < t) ? csr[i + 8]  : zrow;
        int e5 = (i + 10 < t) ? csr[i + 10] : zrow;
        int e6 = (i + 12 < t) ? csr[i + 12] : zrow;
        int e7 = (i + 14 < t) ? csr[i + 14] : zrow;
        uint4 d0 = tbl4[(size_t)e0 * 32 + l32];
        uint4 d1 = tbl4[(size_t)e1 * 32 + l32];
        uint4 d2 = tbl4[(size_t)e2 * 32 + l32];
        uint4 d3 = tbl4[(size_t)e3 * 32 + l32];
        uint4 d4 = tbl4[(size_t)e4 * 32 + l32];
        uint4 d5 = tbl4[(size_t)e5 * 32 + l32];
        uint4 d6 = tbl4[(size_t)e6 * 32 + l32];
        uint4 d7 = tbl4[(size_t)e7 * 32 + l32];
        acc_bf8(d0, a); acc_bf8(d1, a); acc_bf8(d2, a); acc_bf8(d3, a);
        acc_bf8(d4, a); acc_bf8(d5, a); acc_bf8(d6, a); acc_bf8(d7, a);
    }
}

__global__ __launch_bounds__(256) void zero_kernel(float4* __restrict__ p, int n4) {
    int i = blockIdx.x * 256 + threadIdx.x;
    if (i < n4) p[i] = make_float4(0.f, 0.f, 0.f, 0.f);
}

// f32 -> bf16 cast (8 elems/thread); slots [src_n8, n8) zero-filled (sentinel)
__global__ __launch_bounds__(256) void cast_bf16_kernel(const float4* __restrict__ src4,
                                                        uint4* __restrict__ dst4,
                                                        int src_n8, int n8) {
    int i = blockIdx.x * 256 + threadIdx.x;
    if (i >= n8) return;
    uint4 o = {0u, 0u, 0u, 0u};
    if (i < src_n8) {
        float4 f0 = src4[2 * i], f1 = src4[2 * i + 1];
        o.x = f2bf(f0.x) | ((unsigned)f2bf(f0.y) << 16);
        o.y = f2bf(f0.z) | ((unsigned)f2bf(f0.w) << 16);
        o.z = f2bf(f1.x) | ((unsigned)f2bf(f1.y) << 16);
        o.w = f2bf(f1.z) | ((unsigned)f2bf(f1.w) << 16);
    }
    dst4[i] = o;
}

// coarse histogram: per-block LDS hist, one global atomic per (block,bucket)
__global__ __launch_bounds__(256) void coarse_count_kernel(const int* __restrict__ node_idx,
                                                           const int* __restrict__ edge_idx,
                                                           int* __restrict__ cc_e,
                                                           int* __restrict__ cc_n) {
    __shared__ int he[NB], hn[NB];
    int tid = threadIdx.x;
    int base = blockIdx.x * CHUNK;
    for (int i = tid; i < NB; i += 256) { he[i] = 0; hn[i] = 0; }
    __syncthreads();
    for (int i = tid; i < CHUNK; i += 256) {
        atomicAdd(&he[edge_idx[base + i] / EB_E], 1);
        atomicAdd(&hn[node_idx[base + i] / EB_N], 1);
    }
    __syncthreads();
    for (int k = tid; k < NB; k += 256) {
        if (he[k]) atomicAdd(&cc_e[k], he[k]);
        if (hn[k]) atomicAdd(&cc_n[k], hn[k]);
    }
}

// single-block exclusive scan of both coarse-count arrays -> coarse bases
__global__ __launch_bounds__(256) void coarse_scan_kernel(const int* __restrict__ cc_e,
                                                          const int* __restrict__ cc_n,
                                                          int* __restrict__ cb_e,
                                                          int* __restrict__ cb_n) {
    __shared__ int tmp[256];
    int tid = threadIdx.x;
    int v = (tid < NB) ? cc_e[tid] : 0;
    tmp[tid] = v;
    __syncthreads();
    for (int off = 1; off < 256; off <<= 1) {
        int t = (tid >= off) ? tmp[tid - off] : 0;
        __syncthreads();
        tmp[tid] += t;
        __syncthreads();
    }
    if (tid < NB) cb_e[tid + 1] = tmp[tid];
    if (tid == 0) cb_e[0] = 0;
    __syncthreads();
    v = (tid < NB) ? cc_n[tid] : 0;
    tmp[tid] = v;
    __syncthreads();
    for (int off = 1; off < 256; off <<= 1) {
        int t = (tid >= off) ? tmp[tid - off] : 0;
        __syncthreads();
        tmp[tid] += t;
        __syncthreads();
    }
    if (tid < NB) cb_n[tid + 1] = tmp[tid];
    if (tid == 0) cb_n[0] = 0;
}

// pass 1: scatter incidences into coarse buckets (both sides), line-dense writes
__global__ __launch_bounds__(256) void bucket_scatter_kernel(const int* __restrict__ node_idx,
                                                             const int* __restrict__ edge_idx,
                                                             const int* __restrict__ cb_e,
                                                             const int* __restrict__ cb_n,
                                                             int* __restrict__ cur_e,
                                                             int* __restrict__ cur_n,
                                                             int* __restrict__ buf_e,
                                                             int* __restrict__ buf_n) {
    __shared__ int he[NB], hn[NB], be[NB], bn[NB];
    int tid = threadIdx.x;
    int base = blockIdx.x * CHUNK;
    for (int i = tid; i < NB; i += 256) { he[i] = 0; hn[i] = 0; }
    __syncthreads();
    for (int i = tid; i < CHUNK; i += 256) {
        int e = edge_idx[base + i], v = node_idx[base + i];
        atomicAdd(&he[e / EB_E], 1);
        atomicAdd(&hn[v / EB_N], 1);
    }
    __syncthreads();
    for (int k = tid; k < NB; k += 256) {
        int c = he[k];
        be[k] = cb_e[k] + (c ? atomicAdd(&cur_e[k], c) : 0);
        int cn = hn[k];
        bn[k] = cb_n[k] + (cn ? atomicAdd(&cur_n[k], cn) : 0);
    }
    __syncthreads();
    for (int i = tid; i < NB; i += 256) { he[i] = 0; hn[i] = 0; }
    __syncthreads();
    for (int i = tid; i < CHUNK; i += 256) {
        int e = edge_idx[base + i], v = node_idx[base + i];
        int ke = e / EB_E, kn = v / EB_N;
        int oe = atomicAdd(&he[ke], 1);
        buf_e[be[ke] + oe] = (v << 6) | (e - ke * EB_E);
        int on = atomicAdd(&hn[kn], 1);
        buf_n[bn[kn] + on] = (e << 8) | (v - kn * EB_N);
    }
}

// pass 2: per-bucket LDS counting sort -> final CSR + emit fine rs
__global__ __launch_bounds__(256) void bucket_sort_kernel(const int* __restrict__ buf_e,
                                                          const int* __restrict__ buf_n,
                                                          const int* __restrict__ cb_e,
                                                          const int* __restrict__ cb_n,
                                                          int* __restrict__ csr_e,
                                                          int* __restrict__ csr_n,
                                                          int* __restrict__ rs_e,
                                                          int* __restrict__ rs_n) {
    __shared__ int A[CAP];
    __shared__ int h[EB_N], bs[EB_N];
    int tid = threadIdx.x;
    bool edgeSide = blockIdx.x < NB;
    int k = edgeSide ? blockIdx.x : blockIdx.x - NB;
    int eb = edgeSide ? EB_E : EB_N;
    int shift = edgeSide ? 6 : 8;
    int mask = (1 << shift) - 1;
    const int* cb  = edgeSide ? cb_e : cb_n;
    const int* buf = edgeSide ? buf_e : buf_n;
    int* csr       = edgeSide ? csr_e : csr_n;
    int* rs        = edgeSide ? rs_e : rs_n;
    int base = cb[k];
    int cnt = cb[k + 1] - base;
    for (int i = tid; i < eb; i += 256) h[i] = 0;
    __syncthreads();
    for (int i = tid; i < cnt; i += 256) {
        int it = buf[base + i];
        if (i < CAP) A[i] = it;
        atomicAdd(&h[it & mask], 1);
    }
    __syncthreads();
    if (tid == 0) {
        int s = 0;
        for (int j = 0; j < eb; j++) { bs[j] = s; s += h[j]; }
    }
    __syncthreads();
    for (int j = tid; j < eb; j += 256) {
        rs[k * eb + j] = base + bs[j];
        h[j] = 0;
    }
    if (tid == 0 && k == NB - 1) rs[edgeSide ? N_EDGES : N_NODES] = NNZ;
    __syncthreads();
    for (int i = tid; i < cnt; i += 256) {
        int it = (i < CAP) ? A[i] : buf[base + i];
        int loc = it & mask;
        int off = bs[loc] + atomicAdd(&h[loc], 1);
        csr[base + off] = it >> shift;
    }
}

// one wave per hyperedge; masked 8-deep gathers; bf16 output (pad rows zeroed)
__global__ __launch_bounds__(256) void edge_aggregate_kernel(const uint4* __restrict__ embh4,
                                                             const int* __restrict__ csr_e,
                                                             const int* __restrict__ rs_e,
                                                             unsigned short* __restrict__ e_acc_h) {
    int e = blockIdx.x * 4 + (threadIdx.x >> 6);
    int lane = threadIdx.x & 63;
    int half = lane >> 5, l32 = lane & 31;
    int s = 0, t = 0;
    if (e < N_EDGES) { s = rs_e[e]; t = rs_e[e + 1]; }
    float a[8] = {0.f, 0.f, 0.f, 0.f, 0.f, 0.f, 0.f, 0.f};
    gather8(embh4, csr_e, s, t, half, l32, N_NODES, a);
    #pragma unroll
    for (int j = 0; j < 8; j++) a[j] += __shfl_xor(a[j], 32);
    if (half == 0) {
        uint4 o;
        o.x = f2bf(a[0]) | ((unsigned)f2bf(a[1]) << 16);
        o.y = f2bf(a[2]) | ((unsigned)f2bf(a[3]) << 16);
        o.z = f2bf(a[4]) | ((unsigned)f2bf(a[5]) << 16);
        o.w = f2bf(a[6]) | ((unsigned)f2bf(a[7]) << 16);
        ((uint4*)(e_acc_h + (size_t)e * C))[l32] = o;
    }
}

// e2[m][n] = Binv[m] * sum_k e_acc[m][k] * conv_w[n][k] via MFMA; grid (157,4)
// pad rows (m >= N_EDGES) stored ZERO -> e2h row N_EDGES is the sentinel
__global__ __launch_bounds__(256) void edge_gemm_mfma_kernel(const unsigned short* __restrict__ e_acc_h,
                                                             const unsigned short* __restrict__ cwh,
                                                             const int* __restrict__ rs_e,
                                                             unsigned short* __restrict__ e2h) {
    __shared__ __align__(16) unsigned short As[64 * 72];
    __shared__ __align__(16) unsigned short Bs[64 * 72];
    int i0 = blockIdx.x * 64, j0 = blockIdx.y * 64;
    int tid = threadIdx.x;
    int w = tid >> 6, lane = tid & 63;
    int col = lane & 15, quad = lane >> 4;
    floatx4 acc[4] = {};
    for (int step = 0; step < 4; step++) {
        int kb = step * 64;
        __syncthreads();
        #pragma unroll
        for (int l = 0; l < 2; l++) {
            int slot = tid + l * 256;
            int row = slot >> 3, grp = slot & 7;
            uint4 da = *(const uint4*)(e_acc_h + (size_t)(i0 + row) * C + kb + grp * 8);
            *(uint4*)(&As[row * 72 + grp * 8]) = da;
            uint4 db = *(const uint4*)(cwh + (size_t)(j0 + row) * C + kb + grp * 8);
            *(uint4*)(&Bs[row * 72 + grp * 8]) = db;
        }
        __syncthreads();
        #pragma unroll
        for (int sub = 0; sub < 2; sub++) {
            short8 a = *(const short8*)(&As[(w * 16 + col) * 72 + sub * 32 + quad * 8]);
            #pragma unroll
            for (int jt = 0; jt < 4; jt++) {
                short8 b = *(const short8*)(&Bs[(jt * 16 + col) * 72 + sub * 32 + quad * 8]);
                acc[jt] = __builtin_amdgcn_mfma_f32_16x16x32_bf16(a, b, acc[jt], 0, 0, 0);
            }
        }
    }
    #pragma unroll
    for (int r = 0; r < 4; r++) {
        int m = i0 + w * 16 + quad * 4 + r;          // < MPAD always
        int deg = (m < N_EDGES) ? rs_e[m + 1] - rs_e[m] : 0;
        float binv = (deg > 0) ? 1.0f / (float)deg : 0.0f;
        #pragma unroll
        for (int jt = 0; jt < 4; jt++)
            e2h[(size_t)m * C + j0 + jt * 16 + col] = f2bf(acc[jt][r] * binv);
    }
}

// 32 nodes per block (4 waves x 8 nodes); masked 4-deep gathers; fused
// Dinv/bias/lrelu; write yT (transposed via LDS)
__global__ __launch_bounds__(256) void node_aggregate_t_kernel(const uint4* __restrict__ e2h4,
                                                               const int* __restrict__ csr_n,
                                                               const int* __restrict__ rs_n,
                                                               const float* __restrict__ conv_b,
                                                               unsigned short* __restrict__ yT) {
    __shared__ __align__(16) unsigned short T[32][256];  // [node][ch]
    int n0 = blockIdx.x * 32;
    int tid = threadIdx.x;
    int w = tid >> 6, lane = tid & 63;
    int half = lane >> 5, l32 = lane & 31;
    int base = n0 + w * 8;
    // __shfl below runs with ALL 64 lanes active (uniform q loop) — safe
    int rsv = rs_n[min(base + lane, N_NODES)];
    float4 b0 = ((const float4*)conv_b)[l32 * 2];
    float4 b1 = ((const float4*)conv_b)[l32 * 2 + 1];
    float bb[8] = {b0.x, b0.y, b0.z, b0.w, b1.x, b1.y, b1.z, b1.w};
    for (int q = 0; q < 8; q++) {
        int v = base + q;
        int s = __shfl(rsv, q), t = __shfl(rsv, q + 1);
        float a[8] = {0.f, 0.f, 0.f, 0.f, 0.f, 0.f, 0.f, 0.f};
        gather4(e2h4, csr_n, s, t, half, l32, N_EDGES, a);
        #pragma unroll
        for (int j = 0; j < 8; j++) a[j] += __shfl_xor(a[j], 32);
        float dinv = (t > s) ? 1.0f / (float)(t - s) : 0.0f;
        unsigned int pk[4];
        #pragma unroll
        for (int j = 0; j < 4; j++) {
            float r0 = a[2 * j] * dinv + bb[2 * j];
            float r1 = a[2 * j + 1] * dinv + bb[2 * j + 1];
            r0 = (r0 > 0.f) ? r0 : SLOPE * r0;
            r1 = (r1 > 0.f) ? r1 : SLOPE * r1;
            if (v >= N_NODES) { r0 = 0.f; r1 = 0.f; }   // zero-pad rows
            pk[j] = f2bf(r0) | ((unsigned)f2bf(r1) << 16);
        }
        if (half == 0) {
            uint4 o; o.x = pk[0]; o.y = pk[1]; o.z = pk[2]; o.w = pk[3];
            *(uint4*)(&T[w * 8 + q][l32 * 8]) = o;
        }
    }
    __syncthreads();
    int ch = tid;
    #pragma unroll
    for (int jj = 0; jj < 4; jj++) {
        uint4 o;
        o.x = T[jj * 8 + 0][ch] | ((unsigned)T[jj * 8 + 1][ch] << 16);
        o.y = T[jj * 8 + 2][ch] | ((unsigned)T[jj * 8 + 3][ch] << 16);
        o.z = T[jj * 8 + 4][ch] | ((unsigned)T[jj * 8 + 5][ch] << 16);
        o.w = T[jj * 8 + 6][ch] | ((unsigned)T[jj * 8 + 7][ch] << 16);
        *(uint4*)(yT + (size_t)ch * KTOT + n0 + jj * 8) = o;
    }
}

// Gram partials via MFMA, symmetry-aware (10 upper-tri tile pairs), NO atomics:
// each block writes a private 4096-float slab. grid (10, NZB). Diagonal pairs
// stage only A (B == A).
__global__ __launch_bounds__(256) void gram_mfma_kernel(const unsigned short* __restrict__ yT,
                                                        float* __restrict__ part) {
    static const int PI[10] = {0, 0, 0, 0, 1, 1, 1, 2, 2, 3};
    static const int PJ[10] = {0, 1, 2, 3, 1, 2, 3, 2, 3, 3};
    __shared__ __align__(16) unsigned short As[64 * 72];  // [col][k], stride 72
    __shared__ __align__(16) unsigned short Bs[64 * 72];
    int i0 = PI[blockIdx.x] * 64, j0 = PJ[blockIdx.x] * 64;
    bool diag = (i0 == j0);
    int kb0 = blockIdx.y * KCHUNK;
    int tid = threadIdx.x;
    int w = tid >> 6, lane = tid & 63;
    int col = lane & 15, quad = lane >> 4;
    floatx4 acc[4] = {};
    for (int step = 0; step < KCHUNK / 64; step++) {
        int kb = kb0 + step * 64;
        __syncthreads();
        #pragma unroll
        for (int l = 0; l < 2; l++) {
            int slot = tid + l * 256;
            int row = slot >> 3, grp = slot & 7;
            uint4 da = *(const uint4*)(yT + (size_t)(i0 + row) * KTOT + kb + grp * 8);
            *(uint4*)(&As[row * 72 + grp * 8]) = da;
            if (!diag) {
                uint4 db = *(const uint4*)(yT + (size_t)(j0 + row) * KTOT + kb + grp * 8);
                *(uint4*)(&Bs[row * 72 + grp * 8]) = db;
            }
        }
        __syncthreads();
        const unsigned short* Bb = diag ? As : Bs;
        #pragma unroll
        for (int sub = 0; sub < 2; sub++) {
            short8 a = *(const short8*)(&As[(w * 16 + col) * 72 + sub * 32 + quad * 8]);
            #pragma unroll
            for (int jt = 0; jt < 4; jt++) {
                short8 b = *(const short8*)(&Bb[(jt * 16 + col) * 72 + sub * 32 + quad * 8]);
                acc[jt] = __builtin_amdgcn_mfma_f32_16x16x32_bf16(a, b, acc[jt], 0, 0, 0);
            }
        }
    }
    // plain coalesced stores to this block's private slab
    float* slab = part + ((size_t)blockIdx.y * 10 + blockIdx.x) * 4096;
    #pragma unroll
    for (int jt = 0; jt < 4; jt++)
        #pragma unroll
        for (int r = 0; r < 4; r++)
            slab[(w * 16 + quad * 4 + r) * 64 + jt * 16 + col] = acc[jt][r];
}

// g[i][j] = sum_z part[z][tile(i,j)][...], with symmetric mirror. grid (256),
// block = row i, thread = col j.
__global__ __launch_bounds__(256) void greduce_kernel(const float* __restrict__ part,
                                                      float* __restrict__ g) {
    int i = blockIdx.x, j = threadIdx.x;
    int a = i >> 6, b = j >> 6;
    int lo = min(a, b), hi = max(a, b);
    int t = lo * (7 - lo) / 2 + hi;          // pair index in PI/PJ order
    int li = (a <= b) ? (i & 63) : (j & 63);
    int lj = (a <= b) ? (j & 63) : (i & 63);
    const float* p = part + (size_t)t * 4096 + li * 64 + lj;
    float s = 0.f;
    for (int z = 0; z < NZB; z++) s += p[(size_t)z * 40960];
    g[(size_t)i * C + j] = s;
}

__global__ __launch_bounds__(256) void out_kernel(const float* __restrict__ g,
                                                  const float* __restrict__ lin_w,
                                                  const float* __restrict__ lin_b,
                                                  float* __restrict__ out) {
    __shared__ float gs[C];
    int i = blockIdx.x, j = threadIdx.x;
    gs[j] = g[(size_t)i * C + j];
    __syncthreads();
    float acc = lin_b[j];
    const float* wrow = lin_w + (size_t)j * C;
    for (int k = 0; k < C; k++) acc += gs[k] * wrow[k];
    out[(size_t)i * C + j] = (acc > 0.f) ? acc : SLOPE * acc;
}

extern "C" void kernel_launch(void* const* d_in, const int* in_sizes, int n_in,
                              void* d_out, int out_size, void* d_ws, size_t ws_size,
                              hipStream_t stream) {
    const float* emb    = (const float*)d_in[0];
    const float* conv_w = (const float*)d_in[1];
    const float* conv_b = (const float*)d_in[2];
    const float* lin_w  = (const float*)d_in[3];
    const float* lin_b  = (const float*)d_in[4];
    const int*   eidx   = (const int*)d_in[5];
    const int* node_idx = eidx;        // edge_index[0]
    const int* edge_idx = eidx + NNZ;  // edge_index[1]

    char* ws = (char*)d_ws;
    int* cc_e  = (int*)(ws + OFF_CC_E);
    int* cc_n  = (int*)(ws + OFF_CC_N);
    int* cur_e = (int*)(ws + OFF_CUR_E);
    int* cur_n = (int*)(ws + OFF_CUR_N);
    float* g   = (float*)(ws + OFF_G);
    int* cb_e  = (int*)(ws + OFF_CB_E);
    int* cb_n  = (int*)(ws + OFF_CB_N);
    int* rs_n  = (int*)(ws + OFF_RS_N);
    int* rs_e  = (int*)(ws + OFF_RS_E);
    int* buf_e = (int*)(ws + OFF_BUF_E);
    int* buf_n = (int*)(ws + OFF_BUF_N);
    int* csr_e = (int*)(ws + OFF_CSR_E);
    int* csr_n = (int*)(ws + OFF_CSR_N);
    uint4* embh4 = (uint4*)(ws + OFF_EMBH);
    unsigned short* e_acc_h = (unsigned short*)(ws + OFF_EACC);
    unsigned short* e2h = (unsigned short*)(ws + OFF_E2);
    unsigned short* cwh = (unsigned short*)(ws + OFF_CWH);
    unsigned short* yT  = (unsigned short*)(ws + OFF_YT);
    float* part = (float*)(ws + OFF_PART);
    float* out = (float*)d_out;

    int n4 = ZERO_BYTES / 16;   // 256 — counters only
    zero_kernel<<<1, 256, 0, stream>>>((float4*)ws, n4);

    // emb -> bf16 + zero-sentinel row at index N_NODES
    cast_bf16_kernel<<<6251, 256, 0, stream>>>((const float4*)emb, embh4, 1600000, 1600032);
    cast_bf16_kernel<<<32, 256, 0, stream>>>((const float4*)conv_w, (uint4*)cwh, 8192, 8192);

    coarse_count_kernel<<<256, 256, 0, stream>>>(node_idx, edge_idx, cc_e, cc_n);

    coarse_scan_kernel<<<1, 256, 0, stream>>>(cc_e, cc_n, cb_e, cb_n);

    bucket_scatter_kernel<<<256, 256, 0, stream>>>(node_idx, edge_idx, cb_e, cb_n,
                                                   cur_e, cur_n, buf_e, buf_n);

    bucket_sort_kernel<<<2 * NB, 256, 0, stream>>>(buf_e, buf_n, cb_e, cb_n,
                                                   csr_e, csr_n, rs_e, rs_n);

    edge_aggregate_kernel<<<MPAD / 4, 256, 0, stream>>>(embh4, csr_e, rs_e, e_acc_h);

    edge_gemm_mfma_kernel<<<dim3(MPAD / 64, C / 64), 256, 0, stream>>>(e_acc_h, cwh, rs_e, e2h);

    node_aggregate_t_kernel<<<KTOT / 32, 256, 0, stream>>>((const uint4*)e2h, csr_n, rs_n,
                                                           conv_b, yT);

    gram_mfma_kernel<<<dim3(10, NZB), 256, 0, stream>>>(yT, part);

    greduce_kernel<<<C, 256, 0, stream>>>(part, g);

    out_kernel<<<C, 256, 0, stream>>>(g, lin_w, lin_b, out);
}

// Round 11
// 300.667 us; speedup vs baseline: 1.1151x; 1.0214x over previous
//
#include <hip/hip_runtime.h>

#define N_NODES 50000
#define N_EDGES 10000
#define NNZ     800000
#define C       256
#define SLOPE   0.01f
#define KTOT    50176   // node count padded to 512*98
#define KCHUNK  512     // 8 * 64
#define NZB     98      // KTOT / KCHUNK
#define MPAD    10048   // edge count padded to multiple of 64

#define NB      250     // coarse buckets per side
#define EB_E    40      // edges per bucket   (250*40  = 10000)
#define EB_N    200     // nodes per bucket   (250*200 = 50000)
#define CHUNK   3125    // NNZ / 256 blocks
#define CAP     6000    // LDS item capacity in bucket_sort (mean 3200, sd ~57)

// ---- workspace layout (bytes) ----
#define OFF_CC_E    0          // 250*4 coarse counts (edge)
#define OFF_CC_N    1024       // 250*4 coarse counts (node)
#define OFF_CUR_E   2048       // 250*4 scatter cursors
#define OFF_CUR_N   3072       // 250*4
#define ZERO_BYTES  4096       // zero region: counters only
#define OFF_CB_E    266240     // 251*4 coarse bases (edge)
#define OFF_CB_N    267264     // 251*4 coarse bases (node)
#define OFF_RS_N    268288     // 50001*4 (written by bucket_sort)
#define OFF_RS_E    468480     // 10001*4 (written by bucket_sort)
#define OFF_BUF_E   508672     // 800000*4 bucketed items (edge side)
#define OFF_BUF_N   3708672    // 800000*4 bucketed items (node side)
#define OFF_CSR_E   6908672    // 800000*4 node ids grouped by edge
#define OFF_CSR_N   10108672   // 800000*4 edge ids grouped by node
#define OFF_EMBH    13308672   // 50001*256*2 bf16 incl zero-sentinel row 50000
#define OFF_YT      13308672   // 256*50176*2 bf16 — ALIASES embh (embh dead before
                               // node_aggregate writes yT); ends 38,998,784
#define OFF_EACC    39000064   // 10048*256*2 bf16 (dead after edge_gemm)
#define OFF_E2      44144640   // 10048*256*2 bf16; rows 10000.. ZERO (sentinel)
#define OFF_CWH     49289216   // 256*256*2 bf16 conv_w
#define OFF_PART    49420288   // 98*10*4096*4 gram partials -> end 65,476,608

typedef __attribute__((ext_vector_type(8))) short short8;
typedef __attribute__((ext_vector_type(4))) float floatx4;

static __device__ __forceinline__ unsigned short f2bf(float f) {
    unsigned int u = __float_as_uint(f);
    u = (u + 0x7fffu + ((u >> 16) & 1u)) >> 16;   // RNE
    return (unsigned short)u;
}

// unpack uint4 (8 bf16) and accumulate into a[0..7]
static __device__ __forceinline__ void acc_bf8(const uint4 d, float* a) {
    a[0] += __uint_as_float(d.x << 16);
    a[1] += __uint_as_float(d.x & 0xffff0000u);
    a[2] += __uint_as_float(d.y << 16);
    a[3] += __uint_as_float(d.y & 0xffff0000u);
    a[4] += __uint_as_float(d.z << 16);
    a[5] += __uint_as_float(d.z & 0xffff0000u);
    a[6] += __uint_as_float(d.w << 16);
    a[7] += __uint_as_float(d.w & 0xffff0000u);
}

// Masked 4-deep gather; OOB slots clamped to zero-sentinel row `zrow`.
static __device__ __forceinline__ void gather4(const uint4* __restrict__ tbl4,
                                               const int* __restrict__ csr,
                                               int s, int t, int half, int l32,
                                               int zrow, float* a) {
    for (int i = s + half; i < t; i += 8) {
        int e0 = csr[i];
        int e1 = (i + 2 < t) ? csr[i + 2] : zrow;
        int e2 = (i + 4 < t) ? csr[i + 4] : zrow;
        int e3 = (i + 6 < t) ? csr[i + 6] : zrow;
        uint4 d0 = tbl4[(size_t)e0 * 32 + l32];
        uint4 d1 = tbl4[(size_t)e1 * 32 + l32];
        uint4 d2 = tbl4[(size_t)e2 * 32 + l32];
        uint4 d3 = tbl4[(size_t)e3 * 32 + l32];
        acc_bf8(d0, a); acc_bf8(d1, a); acc_bf8(d2, a); acc_bf8(d3, a);
    }
}

// Masked 8-deep gather (edge side: mean 40 items/half-wave)
static __device__ __forceinline__ void gather8(const uint4* __restrict__ tbl4,
                                               const int* __restrict__ csr,
                                               int s, int t, int half, int l32,
                                               int zrow, float* a) {
    for (int i = s + half; i < t; i += 16) {
        int e0 = csr[i];
        int e1 = (i + 2  < t) ? csr[i + 2]  : zrow;
        int e2 = (i + 4  < t) ? csr[i + 4]  : zrow;
        int e3 = (i + 6  < t) ? csr[i + 6]  : zrow;
        int e4 = (i + 8  < t) ? csr[i + 8]  : zrow;
        int e5 = (i + 10 < t) ? csr[i + 10] : zrow;
        int e6 = (i + 12 < t) ? csr[i + 12] : zrow;
        int e7 = (i + 14 < t) ? csr[i + 14] : zrow;
        uint4 d0 = tbl4[(size_t)e0 * 32 + l32];
        uint4 d1 = tbl4[(size_t)e1 * 32 + l32];
        uint4 d2 = tbl4[(size_t)e2 * 32 + l32];
        uint4 d3 = tbl4[(size_t)e3 * 32 + l32];
        uint4 d4 = tbl4[(size_t)e4 * 32 + l32];
        uint4 d5 = tbl4[(size_t)e5 * 32 + l32];
        uint4 d6 = tbl4[(size_t)e6 * 32 + l32];
        uint4 d7 = tbl4[(size_t)e7 * 32 + l32];
        acc_bf8(d0, a); acc_bf8(d1, a); acc_bf8(d2, a); acc_bf8(d3, a);
        acc_bf8(d4, a); acc_bf8(d5, a); acc_bf8(d6, a); acc_bf8(d7, a);
    }
}

__global__ __launch_bounds__(256) void zero_kernel(float4* __restrict__ p, int n4) {
    int i = blockIdx.x * 256 + threadIdx.x;
    if (i < n4) p[i] = make_float4(0.f, 0.f, 0.f, 0.f);
}

// FUSED prep: blocks [0,6251) cast emb->bf16 (+ zero sentinel row),
// [6251,6283) cast conv_w->bf16, [6283,6539) coarse histogram.
#define PREP_EMB_BLOCKS 6251
#define PREP_CW_BLOCKS  32
__global__ __launch_bounds__(256) void prep_kernel(const float4* __restrict__ emb4,
                                                   uint4* __restrict__ embh4,
                                                   const float4* __restrict__ cw4,
                                                   uint4* __restrict__ cwh4,
                                                   const int* __restrict__ node_idx,
                                                   const int* __restrict__ edge_idx,
                                                   int* __restrict__ cc_e,
                                                   int* __restrict__ cc_n) {
    __shared__ int he[NB], hn[NB];
    int b = blockIdx.x, tid = threadIdx.x;
    if (b < PREP_EMB_BLOCKS) {
        int i = b * 256 + tid;
        if (i >= 1600032) return;
        uint4 o = {0u, 0u, 0u, 0u};
        if (i < 1600000) {
            float4 f0 = emb4[2 * i], f1 = emb4[2 * i + 1];
            o.x = f2bf(f0.x) | ((unsigned)f2bf(f0.y) << 16);
            o.y = f2bf(f0.z) | ((unsigned)f2bf(f0.w) << 16);
            o.z = f2bf(f1.x) | ((unsigned)f2bf(f1.y) << 16);
            o.w = f2bf(f1.z) | ((unsigned)f2bf(f1.w) << 16);
        }
        embh4[i] = o;
    } else if (b < PREP_EMB_BLOCKS + PREP_CW_BLOCKS) {
        int i = (b - PREP_EMB_BLOCKS) * 256 + tid;   // < 8192
        float4 f0 = cw4[2 * i], f1 = cw4[2 * i + 1];
        uint4 o;
        o.x = f2bf(f0.x) | ((unsigned)f2bf(f0.y) << 16);
        o.y = f2bf(f0.z) | ((unsigned)f2bf(f0.w) << 16);
        o.z = f2bf(f1.x) | ((unsigned)f2bf(f1.y) << 16);
        o.w = f2bf(f1.z) | ((unsigned)f2bf(f1.w) << 16);
        cwh4[i] = o;
    } else {
        int base = (b - PREP_EMB_BLOCKS - PREP_CW_BLOCKS) * CHUNK;
        for (int i = tid; i < NB; i += 256) { he[i] = 0; hn[i] = 0; }
        __syncthreads();
        for (int i = tid; i < CHUNK; i += 256) {
            atomicAdd(&he[edge_idx[base + i] / EB_E], 1);
            atomicAdd(&hn[node_idx[base + i] / EB_N], 1);
        }
        __syncthreads();
        for (int k = tid; k < NB; k += 256) {
            if (he[k]) atomicAdd(&cc_e[k], he[k]);
            if (hn[k]) atomicAdd(&cc_n[k], hn[k]);
        }
    }
}

// single-block exclusive scan of both coarse-count arrays -> coarse bases
__global__ __launch_bounds__(256) void coarse_scan_kernel(const int* __restrict__ cc_e,
                                                          const int* __restrict__ cc_n,
                                                          int* __restrict__ cb_e,
                                                          int* __restrict__ cb_n) {
    __shared__ int tmp[256];
    int tid = threadIdx.x;
    int v = (tid < NB) ? cc_e[tid] : 0;
    tmp[tid] = v;
    __syncthreads();
    for (int off = 1; off < 256; off <<= 1) {
        int t = (tid >= off) ? tmp[tid - off] : 0;
        __syncthreads();
        tmp[tid] += t;
        __syncthreads();
    }
    if (tid < NB) cb_e[tid + 1] = tmp[tid];
    if (tid == 0) cb_e[0] = 0;
    __syncthreads();
    v = (tid < NB) ? cc_n[tid] : 0;
    tmp[tid] = v;
    __syncthreads();
    for (int off = 1; off < 256; off <<= 1) {
        int t = (tid >= off) ? tmp[tid - off] : 0;
        __syncthreads();
        tmp[tid] += t;
        __syncthreads();
    }
    if (tid < NB) cb_n[tid + 1] = tmp[tid];
    if (tid == 0) cb_n[0] = 0;
}

// pass 1: scatter into coarse buckets. Single LDS-hist pass: the pass-1
// atomicAdd return value IS the local offset — carried in registers
// (13 packed ints/thread), so the placement pass needs no second histogram.
__global__ __launch_bounds__(256) void bucket_scatter_kernel(const int* __restrict__ node_idx,
                                                             const int* __restrict__ edge_idx,
                                                             const int* __restrict__ cb_e,
                                                             const int* __restrict__ cb_n,
                                                             int* __restrict__ cur_e,
                                                             int* __restrict__ cur_n,
                                                             int* __restrict__ buf_e,
                                                             int* __restrict__ buf_n) {
    __shared__ int he[NB], hn[NB], be[NB], bn[NB];
    int tid = threadIdx.x;
    int base = blockIdx.x * CHUNK;
    for (int i = tid; i < NB; i += 256) { he[i] = 0; hn[i] = 0; }
    __syncthreads();
    int pe[13], pn[13];   // (bucket<<12) | local_offset ; offset < 3125 < 4096
    #pragma unroll
    for (int k = 0; k < 13; k++) {
        int i = tid + k * 256;
        if (i < CHUNK) {
            int e = edge_idx[base + i], v = node_idx[base + i];
            int ke = e / EB_E, kn = v / EB_N;
            pe[k] = (ke << 12) | atomicAdd(&he[ke], 1);
            pn[k] = (kn << 12) | atomicAdd(&hn[kn], 1);
        }
    }
    __syncthreads();
    for (int k = tid; k < NB; k += 256) {
        int c = he[k];
        be[k] = cb_e[k] + (c ? atomicAdd(&cur_e[k], c) : 0);
        int cn = hn[k];
        bn[k] = cb_n[k] + (cn ? atomicAdd(&cur_n[k], cn) : 0);
    }
    __syncthreads();
    #pragma unroll
    for (int k = 0; k < 13; k++) {
        int i = tid + k * 256;
        if (i < CHUNK) {
            int e = edge_idx[base + i], v = node_idx[base + i];
            int ke = pe[k] >> 12, oe = pe[k] & 4095;
            buf_e[be[ke] + oe] = (v << 6) | (e - ke * EB_E);
            int kn = pn[k] >> 12, on = pn[k] & 4095;
            buf_n[bn[kn] + on] = (e << 8) | (v - kn * EB_N);
        }
    }
}

// pass 2: per-bucket LDS counting sort -> final CSR + emit fine rs
__global__ __launch_bounds__(256) void bucket_sort_kernel(const int* __restrict__ buf_e,
                                                          const int* __restrict__ buf_n,
                                                          const int* __restrict__ cb_e,
                                                          const int* __restrict__ cb_n,
                                                          int* __restrict__ csr_e,
                                                          int* __restrict__ csr_n,
                                                          int* __restrict__ rs_e,
                                                          int* __restrict__ rs_n) {
    __shared__ int A[CAP];
    __shared__ int h[EB_N], bs[EB_N];
    int tid = threadIdx.x;
    bool edgeSide = blockIdx.x < NB;
    int k = edgeSide ? blockIdx.x : blockIdx.x - NB;
    int eb = edgeSide ? EB_E : EB_N;
    int shift = edgeSide ? 6 : 8;
    int mask = (1 << shift) - 1;
    const int* cb  = edgeSide ? cb_e : cb_n;
    const int* buf = edgeSide ? buf_e : buf_n;
    int* csr       = edgeSide ? csr_e : csr_n;
    int* rs        = edgeSide ? rs_e : rs_n;
    int base = cb[k];
    int cnt = cb[k + 1] - base;
    for (int i = tid; i < eb; i += 256) h[i] = 0;
    __syncthreads();
    for (int i = tid; i < cnt; i += 256) {
        int it = buf[base + i];
        if (i < CAP) A[i] = it;
        atomicAdd(&h[it & mask], 1);
    }
    __syncthreads();
    if (tid == 0) {
        int s = 0;
        for (int j = 0; j < eb; j++) { bs[j] = s; s += h[j]; }
    }
    __syncthreads();
    for (int j = tid; j < eb; j += 256) {
        rs[k * eb + j] = base + bs[j];
        h[j] = 0;
    }
    if (tid == 0 && k == NB - 1) rs[edgeSide ? N_EDGES : N_NODES] = NNZ;
    __syncthreads();
    for (int i = tid; i < cnt; i += 256) {
        int it = (i < CAP) ? A[i] : buf[base + i];
        int loc = it & mask;
        int off = bs[loc] + atomicAdd(&h[loc], 1);
        csr[base + off] = it >> shift;
    }
}

// one wave per hyperedge; masked 8-deep gathers; bf16 output (pad rows zeroed)
__global__ __launch_bounds__(256) void edge_aggregate_kernel(const uint4* __restrict__ embh4,
                                                             const int* __restrict__ csr_e,
                                                             const int* __restrict__ rs_e,
                                                             unsigned short* __restrict__ e_acc_h) {
    int e = blockIdx.x * 4 + (threadIdx.x >> 6);
    int lane = threadIdx.x & 63;
    int half = lane >> 5, l32 = lane & 31;
    int s = 0, t = 0;
    if (e < N_EDGES) { s = rs_e[e]; t = rs_e[e + 1]; }
    float a[8] = {0.f, 0.f, 0.f, 0.f, 0.f, 0.f, 0.f, 0.f};
    gather8(embh4, csr_e, s, t, half, l32, N_NODES, a);
    #pragma unroll
    for (int j = 0; j < 8; j++) a[j] += __shfl_xor(a[j], 32);
    if (half == 0) {
        uint4 o;
        o.x = f2bf(a[0]) | ((unsigned)f2bf(a[1]) << 16);
        o.y = f2bf(a[2]) | ((unsigned)f2bf(a[3]) << 16);
        o.z = f2bf(a[4]) | ((unsigned)f2bf(a[5]) << 16);
        o.w = f2bf(a[6]) | ((unsigned)f2bf(a[7]) << 16);
        ((uint4*)(e_acc_h + (size_t)e * C))[l32] = o;
    }
}

// e2[m][n] = Binv[m] * sum_k e_acc[m][k] * conv_w[n][k] via MFMA; grid (157,4)
// pad rows (m >= N_EDGES) stored ZERO -> e2h row N_EDGES is the sentinel
__global__ __launch_bounds__(256) void edge_gemm_mfma_kernel(const unsigned short* __restrict__ e_acc_h,
                                                             const unsigned short* __restrict__ cwh,
                                                             const int* __restrict__ rs_e,
                                                             unsigned short* __restrict__ e2h) {
    __shared__ __align__(16) unsigned short As[64 * 72];
    __shared__ __align__(16) unsigned short Bs[64 * 72];
    int i0 = blockIdx.x * 64, j0 = blockIdx.y * 64;
    int tid = threadIdx.x;
    int w = tid >> 6, lane = tid & 63;
    int col = lane & 15, quad = lane >> 4;
    floatx4 acc[4] = {};
    for (int step = 0; step < 4; step++) {
        int kb = step * 64;
        __syncthreads();
        #pragma unroll
        for (int l = 0; l < 2; l++) {
            int slot = tid + l * 256;
            int row = slot >> 3, grp = slot & 7;
            uint4 da = *(const uint4*)(e_acc_h + (size_t)(i0 + row) * C + kb + grp * 8);
            *(uint4*)(&As[row * 72 + grp * 8]) = da;
            uint4 db = *(const uint4*)(cwh + (size_t)(j0 + row) * C + kb + grp * 8);
            *(uint4*)(&Bs[row * 72 + grp * 8]) = db;
        }
        __syncthreads();
        #pragma unroll
        for (int sub = 0; sub < 2; sub++) {
            short8 a = *(const short8*)(&As[(w * 16 + col) * 72 + sub * 32 + quad * 8]);
            #pragma unroll
            for (int jt = 0; jt < 4; jt++) {
                short8 b = *(const short8*)(&Bs[(jt * 16 + col) * 72 + sub * 32 + quad * 8]);
                acc[jt] = __builtin_amdgcn_mfma_f32_16x16x32_bf16(a, b, acc[jt], 0, 0, 0);
            }
        }
    }
    #pragma unroll
    for (int r = 0; r < 4; r++) {
        int m = i0 + w * 16 + quad * 4 + r;          // < MPAD always
        int deg = (m < N_EDGES) ? rs_e[m + 1] - rs_e[m] : 0;
        float binv = (deg > 0) ? 1.0f / (float)deg : 0.0f;
        #pragma unroll
        for (int jt = 0; jt < 4; jt++)
            e2h[(size_t)m * C + j0 + jt * 16 + col] = f2bf(acc[jt][r] * binv);
    }
}

// 32 nodes per block (4 waves x 8 nodes); masked 4-deep gathers; fused
// Dinv/bias/lrelu; write yT (transposed via LDS)
__global__ __launch_bounds__(256) void node_aggregate_t_kernel(const uint4* __restrict__ e2h4,
                                                               const int* __restrict__ csr_n,
                                                               const int* __restrict__ rs_n,
                                                               const float* __restrict__ conv_b,
                                                               unsigned short* __restrict__ yT) {
    __shared__ __align__(16) unsigned short T[32][256];  // [node][ch]
    int n0 = blockIdx.x * 32;
    int tid = threadIdx.x;
    int w = tid >> 6, lane = tid & 63;
    int half = lane >> 5, l32 = lane & 31;
    int base = n0 + w * 8;
    // __shfl below runs with ALL 64 lanes active (uniform q loop) — safe
    int rsv = rs_n[min(base + lane, N_NODES)];
    float4 b0 = ((const float4*)conv_b)[l32 * 2];
    float4 b1 = ((const float4*)conv_b)[l32 * 2 + 1];
    float bb[8] = {b0.x, b0.y, b0.z, b0.w, b1.x, b1.y, b1.z, b1.w};
    for (int q = 0; q < 8; q++) {
        int v = base + q;
        int s = __shfl(rsv, q), t = __shfl(rsv, q + 1);
        float a[8] = {0.f, 0.f, 0.f, 0.f, 0.f, 0.f, 0.f, 0.f};
        gather4(e2h4, csr_n, s, t, half, l32, N_EDGES, a);
        #pragma unroll
        for (int j = 0; j < 8; j++) a[j] += __shfl_xor(a[j], 32);
        float dinv = (t > s) ? 1.0f / (float)(t - s) : 0.0f;
        unsigned int pk[4];
        #pragma unroll
        for (int j = 0; j < 4; j++) {
            float r0 = a[2 * j] * dinv + bb[2 * j];
            float r1 = a[2 * j + 1] * dinv + bb[2 * j + 1];
            r0 = (r0 > 0.f) ? r0 : SLOPE * r0;
            r1 = (r1 > 0.f) ? r1 : SLOPE * r1;
            if (v >= N_NODES) { r0 = 0.f; r1 = 0.f; }   // zero-pad rows
            pk[j] = f2bf(r0) | ((unsigned)f2bf(r1) << 16);
        }
        if (half == 0) {
            uint4 o; o.x = pk[0]; o.y = pk[1]; o.z = pk[2]; o.w = pk[3];
            *(uint4*)(&T[w * 8 + q][l32 * 8]) = o;
        }
    }
    __syncthreads();
    int ch = tid;
    #pragma unroll
    for (int jj = 0; jj < 4; jj++) {
        uint4 o;
        o.x = T[jj * 8 + 0][ch] | ((unsigned)T[jj * 8 + 1][ch] << 16);
        o.y = T[jj * 8 + 2][ch] | ((unsigned)T[jj * 8 + 3][ch] << 16);
        o.z = T[jj * 8 + 4][ch] | ((unsigned)T[jj * 8 + 5][ch] << 16);
        o.w = T[jj * 8 + 6][ch] | ((unsigned)T[jj * 8 + 7][ch] << 16);
        *(uint4*)(yT + (size_t)ch * KTOT + n0 + jj * 8) = o;
    }
}

// Gram partials via MFMA, symmetry-aware (10 upper-tri tile pairs), NO atomics:
// each block writes a private 4096-float slab. grid (10, NZB). Diagonal pairs
// stage only A (B == A).
__global__ __launch_bounds__(256) void gram_mfma_kernel(const unsigned short* __restrict__ yT,
                                                        float* __restrict__ part) {
    static const int PI[10] = {0, 0, 0, 0, 1, 1, 1, 2, 2, 3};
    static const int PJ[10] = {0, 1, 2, 3, 1, 2, 3, 2, 3, 3};
    __shared__ __align__(16) unsigned short As[64 * 72];  // [col][k], stride 72
    __shared__ __align__(16) unsigned short Bs[64 * 72];
    int i0 = PI[blockIdx.x] * 64, j0 = PJ[blockIdx.x] * 64;
    bool diag = (i0 == j0);
    int kb0 = blockIdx.y * KCHUNK;
    int tid = threadIdx.x;
    int w = tid >> 6, lane = tid & 63;
    int col = lane & 15, quad = lane >> 4;
    floatx4 acc[4] = {};
    for (int step = 0; step < KCHUNK / 64; step++) {
        int kb = kb0 + step * 64;
        __syncthreads();
        #pragma unroll
        for (int l = 0; l < 2; l++) {
            int slot = tid + l * 256;
            int row = slot >> 3, grp = slot & 7;
            uint4 da = *(const uint4*)(yT + (size_t)(i0 + row) * KTOT + kb + grp * 8);
            *(uint4*)(&As[row * 72 + grp * 8]) = da;
            if (!diag) {
                uint4 db = *(const uint4*)(yT + (size_t)(j0 + row) * KTOT + kb + grp * 8);
                *(uint4*)(&Bs[row * 72 + grp * 8]) = db;
            }
        }
        __syncthreads();
        const unsigned short* Bb = diag ? As : Bs;
        #pragma unroll
        for (int sub = 0; sub < 2; sub++) {
            short8 a = *(const short8*)(&As[(w * 16 + col) * 72 + sub * 32 + quad * 8]);
            #pragma unroll
            for (int jt = 0; jt < 4; jt++) {
                short8 b = *(const short8*)(&Bb[(jt * 16 + col) * 72 + sub * 32 + quad * 8]);
                acc[jt] = __builtin_amdgcn_mfma_f32_16x16x32_bf16(a, b, acc[jt], 0, 0, 0);
            }
        }
    }
    float* slab = part + ((size_t)blockIdx.y * 10 + blockIdx.x) * 4096;
    #pragma unroll
    for (int jt = 0; jt < 4; jt++)
        #pragma unroll
        for (int r = 0; r < 4; r++)
            slab[(w * 16 + quad * 4 + r) * 64 + jt * 16 + col] = acc[jt][r];
}

// FUSED: block i reduces g row i from the 98 partial slabs (with symmetric
// mirror) into LDS, then computes out row i = lrelu(g_row @ lin_w^T + lin_b).
__global__ __launch_bounds__(256) void greduce_out_kernel(const float* __restrict__ part,
                                                          const float* __restrict__ lin_w,
                                                          const float* __restrict__ lin_b,
                                                          float* __restrict__ out) {
    __shared__ float gs[C];
    int i = blockIdx.x, j = threadIdx.x;
    int a = i >> 6, b = j >> 6;
    int lo = min(a, b), hi = max(a, b);
    int t = lo * (7 - lo) / 2 + hi;          // pair index in PI/PJ order
    int li = (a <= b) ? (i & 63) : (j & 63);
    int lj = (a <= b) ? (j & 63) : (i & 63);
    const float* p = part + (size_t)t * 4096 + li * 64 + lj;
    float s = 0.f;
    for (int z = 0; z < NZB; z++) s += p[(size_t)z * 40960];
    gs[j] = s;
    __syncthreads();
    float acc = lin_b[j];
    const float* wrow = lin_w + (size_t)j * C;
    for (int k = 0; k < C; k++) acc += gs[k] * wrow[k];
    out[(size_t)i * C + j] = (acc > 0.f) ? acc : SLOPE * acc;
}

extern "C" void kernel_launch(void* const* d_in, const int* in_sizes, int n_in,
                              void* d_out, int out_size, void* d_ws, size_t ws_size,
                              hipStream_t stream) {
    const float* emb    = (const float*)d_in[0];
    const float* conv_w = (const float*)d_in[1];
    const float* conv_b = (const float*)d_in[2];
    const float* lin_w  = (const float*)d_in[3];
    const float* lin_b  = (const float*)d_in[4];
    const int*   eidx   = (const int*)d_in[5];
    const int* node_idx = eidx;        // edge_index[0]
    const int* edge_idx = eidx + NNZ;  // edge_index[1]

    char* ws = (char*)d_ws;
    int* cc_e  = (int*)(ws + OFF_CC_E);
    int* cc_n  = (int*)(ws + OFF_CC_N);
    int* cur_e = (int*)(ws + OFF_CUR_E);
    int* cur_n = (int*)(ws + OFF_CUR_N);
    int* cb_e  = (int*)(ws + OFF_CB_E);
    int* cb_n  = (int*)(ws + OFF_CB_N);
    int* rs_n  = (int*)(ws + OFF_RS_N);
    int* rs_e  = (int*)(ws + OFF_RS_E);
    int* buf_e = (int*)(ws + OFF_BUF_E);
    int* buf_n = (int*)(ws + OFF_BUF_N);
    int* csr_e = (int*)(ws + OFF_CSR_E);
    int* csr_n = (int*)(ws + OFF_CSR_N);
    uint4* embh4 = (uint4*)(ws + OFF_EMBH);
    unsigned short* e_acc_h = (unsigned short*)(ws + OFF_EACC);
    unsigned short* e2h = (unsigned short*)(ws + OFF_E2);
    unsigned short* cwh = (unsigned short*)(ws + OFF_CWH);
    unsigned short* yT  = (unsigned short*)(ws + OFF_YT);
    float* part = (float*)(ws + OFF_PART);
    float* out = (float*)d_out;

    zero_kernel<<<1, 256, 0, stream>>>((float4*)ws, ZERO_BYTES / 16);

    prep_kernel<<<PREP_EMB_BLOCKS + PREP_CW_BLOCKS + 256, 256, 0, stream>>>(
        (const float4*)emb, embh4, (const float4*)conv_w, (uint4*)cwh,
        node_idx, edge_idx, cc_e, cc_n);

    coarse_scan_kernel<<<1, 256, 0, stream>>>(cc_e, cc_n, cb_e, cb_n);

    bucket_scatter_kernel<<<256, 256, 0, stream>>>(node_idx, edge_idx, cb_e, cb_n,
                                                   cur_e, cur_n, buf_e, buf_n);

    bucket_sort_kernel<<<2 * NB, 256, 0, stream>>>(buf_e, buf_n, cb_e, cb_n,
                                                   csr_e, csr_n, rs_e, rs_n);

    edge_aggregate_kernel<<<MPAD / 4, 256, 0, stream>>>(embh4, csr_e, rs_e, e_acc_h);

    edge_gemm_mfma_kernel<<<dim3(MPAD / 64, C / 64), 256, 0, stream>>>(e_acc_h, cwh, rs_e, e2h);

    node_aggregate_t_kernel<<<KTOT / 32, 256, 0, stream>>>((const uint4*)e2h, csr_n, rs_n,
                                                           conv_b, yT);

    gram_mfma_kernel<<<dim3(10, NZB), 256, 0, stream>>>(yT, part);

    greduce_out_kernel<<<C, 256, 0, stream>>>(part, lin_w, lin_b, out);
}